// Round 1
// baseline (3727.307 us; speedup 1.0000x reference)
//
#include <hip/hip_runtime.h>

constexpr int N_NODES     = 50000;
constexpr int N_EDGES     = 800000;
constexpr int IN_FEAT     = 96;
constexpr int NUM_CLASSES = 40;
constexpr int FCH = IN_FEAT / 4;      // 24 float4 chunks per feature row
constexpr int CCH = NUM_CLASSES / 4;  // 10 float4 chunks per class row

__device__ __forceinline__ void atomAddF(float* p, float v) {
    // native global_atomic_add_f32 (no CAS loop) on gfx90a+
    unsafeAtomicAdd(p, v);
}

__global__ void init_deg_k(float* __restrict__ deg) {
    int i = blockIdx.x * blockDim.x + threadIdx.x;
    if (i < N_NODES) deg[i] = 1.0f;  // self-loop weight
}

__global__ void scatter_deg_k(const int* __restrict__ col, const float* __restrict__ w,
                              float* __restrict__ deg) {
    int e = blockIdx.x * blockDim.x + threadIdx.x;
    if (e < N_EDGES) atomAddF(&deg[col[e]], w[e]);
}

__global__ void finish_dinv_k(float* __restrict__ deg) {
    int i = blockIdx.x * blockDim.x + threadIdx.x;
    if (i < N_NODES) {
        float d = deg[i];
        deg[i] = d > 0.0f ? rsqrtf(d) : 0.0f;
    }
}

__global__ void norm_k(const int* __restrict__ row, const int* __restrict__ col,
                       const float* __restrict__ w, const float* __restrict__ dinv,
                       float* __restrict__ norm) {
    int e = blockIdx.x * blockDim.x + threadIdx.x;
    if (e < N_EDGES) norm[e] = dinv[row[e]] * w[e] * dinv[col[e]];
}

// h_out[col[e]][:] += norm[e] * h_in[row[e]][:]   (edge-parallel, float4 chunks)
__global__ void sgc_scatter_k(const int* __restrict__ row, const int* __restrict__ col,
                              const float* __restrict__ norm,
                              const float* __restrict__ hin, float* __restrict__ hout) {
    int idx = blockIdx.x * blockDim.x + threadIdx.x;
    if (idx >= N_EDGES * FCH) return;       // 19.2M
    int e = idx / FCH;
    int j = idx - e * FCH;
    int r = row[e], c = col[e];
    float nv = norm[e];
    float4 v = *reinterpret_cast<const float4*>(hin + r * IN_FEAT + j * 4);
    float* dst = hout + c * IN_FEAT + j * 4;
    atomAddF(dst + 0, nv * v.x);
    atomAddF(dst + 1, nv * v.y);
    atomAddF(dst + 2, nv * v.z);
    atomAddF(dst + 3, nv * v.w);
}

// h_out[i][:] += dinv[i]^2 * h_in[i][:]   (self-loop term; plain RMW, no contention)
__global__ void sgc_self_k(const float* __restrict__ hin, const float* __restrict__ dinv,
                           float* __restrict__ hout) {
    int idx = blockIdx.x * blockDim.x + threadIdx.x;
    if (idx >= N_NODES * FCH) return;       // 1.2M
    int i = idx / FCH;
    int j = idx - i * FCH;
    float s = dinv[i];
    s *= s;
    const float* src = hin + i * IN_FEAT + j * 4;
    float* dst = hout + i * IN_FEAT + j * 4;
    float4 v = *reinterpret_cast<const float4*>(src);
    float4 o = *reinterpret_cast<float4*>(dst);
    o.x += s * v.x; o.y += s * v.y; o.z += s * v.z; o.w += s * v.w;
    *reinterpret_cast<float4*>(dst) = o;
}

// out[i][c] = b[c] + sum_f h[i][f] * W[f][c]
__global__ void dense_k(const float* __restrict__ h, const float* __restrict__ Wm,
                        const float* __restrict__ bias, float* __restrict__ out) {
    int idx = blockIdx.x * blockDim.x + threadIdx.x;
    if (idx >= N_NODES * NUM_CLASSES) return;   // 2M
    int i = idx / NUM_CLASSES;
    int c = idx - i * NUM_CLASSES;
    float acc = bias[c];
    const float* hr = h + i * IN_FEAT;
#pragma unroll 8
    for (int f = 0; f < IN_FEAT; ++f)
        acc = fmaf(hr[f], Wm[f * NUM_CLASSES + c], acc);
    out[idx] = acc;
}

__global__ void lpa_init_k(const int* __restrict__ y, const int* __restrict__ mask,
                           float* __restrict__ l) {
    int idx = blockIdx.x * blockDim.x + threadIdx.x;
    if (idx >= N_NODES * NUM_CLASSES) return;   // 2M
    int i = idx / NUM_CLASSES;
    int c = idx - i * NUM_CLASSES;
    l[idx] = (mask[i] != 0 && y[i] == c) ? 1.0f : 0.0f;
}

// l_out[col[e]][:] += w[e] * l_in[row[e]][:]
__global__ void lpa_scatter_k(const int* __restrict__ row, const int* __restrict__ col,
                              const float* __restrict__ w,
                              const float* __restrict__ lin, float* __restrict__ lout) {
    int idx = blockIdx.x * blockDim.x + threadIdx.x;
    if (idx >= N_EDGES * CCH) return;       // 8M
    int e = idx / CCH;
    int j = idx - e * CCH;
    int r = row[e], c = col[e];
    float wv = w[e];
    float4 v = *reinterpret_cast<const float4*>(lin + r * NUM_CLASSES + j * 4);
    float* dst = lout + c * NUM_CLASSES + j * 4;
    atomAddF(dst + 0, wv * v.x);
    atomAddF(dst + 1, wv * v.y);
    atomAddF(dst + 2, wv * v.z);
    atomAddF(dst + 3, wv * v.w);
}

extern "C" void kernel_launch(void* const* d_in, const int* in_sizes, int n_in,
                              void* d_out, int out_size, void* d_ws, size_t ws_size,
                              hipStream_t stream) {
    const float* x    = (const float*)d_in[0];                 // [50000,96]
    const int*   ei   = (const int*)d_in[1];                   // [2,800000]
    const int*   row  = ei;
    const int*   col  = ei + N_EDGES;
    const int*   y    = (const int*)d_in[2];                   // [50000]
    const int*   mask = (const int*)d_in[3];                   // [50000] bool->int
    const float* ew   = (const float*)d_in[4];                 // [800000]
    const float* Wm   = (const float*)d_in[5];                 // [96,40]
    const float* bias = (const float*)d_in[6];                 // [40]
    float* out  = (float*)d_out;                               // [2M sgc | 2M lpa]
    float* lpa_out = out + N_NODES * NUM_CLASSES;

    float* ws   = (float*)d_ws;
    float* dinv = ws;                       // 50048  (deg -> dinv in place)
    float* norm = dinv + 50048;             // 800000
    float* h1   = norm + 800000;            // 4.8M
    float* h2   = h1 + N_NODES * IN_FEAT;   // 4.8M
    float* l0   = h2 + N_NODES * IN_FEAT;   // 2M
    float* l1   = l0 + N_NODES * NUM_CLASSES; // 2M

    const int B = 256;
    auto g = [](long long n, int b) { return (int)((n + b - 1) / b); };

    // ---- gcn_norm with self-loops ----
    init_deg_k<<<g(N_NODES, B), B, 0, stream>>>(dinv);
    scatter_deg_k<<<g(N_EDGES, B), B, 0, stream>>>(col, ew, dinv);
    finish_dinv_k<<<g(N_NODES, B), B, 0, stream>>>(dinv);
    norm_k<<<g(N_EDGES, B), B, 0, stream>>>(row, col, ew, dinv, norm);

    // ---- SGC hop 1: x -> h1 ----
    hipMemsetAsync(h1, 0, (size_t)N_NODES * IN_FEAT * sizeof(float), stream);
    sgc_scatter_k<<<g((long long)N_EDGES * FCH, B), B, 0, stream>>>(row, col, norm, x, h1);
    sgc_self_k<<<g((long long)N_NODES * FCH, B), B, 0, stream>>>(x, dinv, h1);

    // ---- SGC hop 2: h1 -> h2 ----
    hipMemsetAsync(h2, 0, (size_t)N_NODES * IN_FEAT * sizeof(float), stream);
    sgc_scatter_k<<<g((long long)N_EDGES * FCH, B), B, 0, stream>>>(row, col, norm, h1, h2);
    sgc_self_k<<<g((long long)N_NODES * FCH, B), B, 0, stream>>>(h1, dinv, h2);

    // ---- dense head: out[:2M] = h2 @ W + b ----
    dense_k<<<g((long long)N_NODES * NUM_CLASSES, B), B, 0, stream>>>(h2, Wm, bias, out);

    // ---- LPA: init + 3 raw weighted propagations ----
    lpa_init_k<<<g((long long)N_NODES * NUM_CLASSES, B), B, 0, stream>>>(y, mask, l0);

    hipMemsetAsync(l1, 0, (size_t)N_NODES * NUM_CLASSES * sizeof(float), stream);
    lpa_scatter_k<<<g((long long)N_EDGES * CCH, B), B, 0, stream>>>(row, col, ew, l0, l1);

    hipMemsetAsync(l0, 0, (size_t)N_NODES * NUM_CLASSES * sizeof(float), stream);
    lpa_scatter_k<<<g((long long)N_EDGES * CCH, B), B, 0, stream>>>(row, col, ew, l1, l0);

    hipMemsetAsync(lpa_out, 0, (size_t)N_NODES * NUM_CLASSES * sizeof(float), stream);
    lpa_scatter_k<<<g((long long)N_EDGES * CCH, B), B, 0, stream>>>(row, col, ew, l0, lpa_out);
}

// Round 4
// 554.240 us; speedup vs baseline: 6.7251x; 6.7251x over previous
//
#include <hip/hip_runtime.h>

constexpr int N_NODES     = 50000;
constexpr int N_EDGES     = 800000;
constexpr int IN_FEAT     = 96;
constexpr int NUM_CLASSES = 40;
constexpr int FCH = IN_FEAT / 4;      // 24 float4 chunks per feature row
constexpr int CCH = NUM_CLASSES / 4;  // 10 float4 chunks per class row

__device__ __forceinline__ void atomAddF(float* p, float v) {
    unsafeAtomicAdd(p, v);  // native global_atomic_add_f32
}

// ---------------- CSR build (counting sort by destination) ----------------

__global__ void count_k(const int* __restrict__ col, int* __restrict__ cnt) {
    int e = blockIdx.x * blockDim.x + threadIdx.x;
    if (e < N_EDGES) atomicAdd(&cnt[col[e]], 1);
}

// single-block exclusive scan: cnt[0..N_NODES) -> rowptr[0..N_NODES]
__global__ __launch_bounds__(1024) void scan_k(const int* __restrict__ cnt,
                                               int* __restrict__ rowptr) {
    __shared__ int buf[1024];
    __shared__ int carry_s;
    int tid = threadIdx.x;
    if (tid == 0) carry_s = 0;
    __syncthreads();
    for (int base = 0; base < N_NODES; base += 1024) {
        int i = base + tid;
        int v = (i < N_NODES) ? cnt[i] : 0;
        buf[tid] = v;
        __syncthreads();
        for (int off = 1; off < 1024; off <<= 1) {
            int t = (tid >= off) ? buf[tid - off] : 0;
            __syncthreads();
            buf[tid] += t;
            __syncthreads();
        }
        int incl  = buf[tid];
        int total = buf[1023];
        int c     = carry_s;
        if (i < N_NODES) rowptr[i] = c + incl - v;   // exclusive
        __syncthreads();
        if (tid == 0) carry_s = c + total;
        __syncthreads();
    }
    if (tid == 0) rowptr[N_NODES] = carry_s;         // == N_EDGES
}

__global__ void copy_cursor_k(const int* __restrict__ rowptr, int* __restrict__ cursor) {
    int i = blockIdx.x * blockDim.x + threadIdx.x;
    if (i < N_NODES) cursor[i] = rowptr[i];
}

// ---------------- gcn_norm pieces ----------------

__global__ void init_deg_k(float* __restrict__ deg) {
    int i = blockIdx.x * blockDim.x + threadIdx.x;
    if (i < N_NODES) deg[i] = 1.0f;  // self-loop weight
}

__global__ void scatter_deg_k(const int* __restrict__ col, const float* __restrict__ w,
                              float* __restrict__ deg) {
    int e = blockIdx.x * blockDim.x + threadIdx.x;
    if (e < N_EDGES) atomAddF(&deg[col[e]], w[e]);
}

__global__ void finish_dinv_k(float* __restrict__ deg) {
    int i = blockIdx.x * blockDim.x + threadIdx.x;
    if (i < N_NODES) {
        float d = deg[i];
        deg[i] = d > 0.0f ? rsqrtf(d) : 0.0f;
    }
}

// scatter edges into CSR slots; store src, gcn-norm weight, and raw weight
__global__ void csr_build_k(const int* __restrict__ row, const int* __restrict__ col,
                            const float* __restrict__ ew, const float* __restrict__ dinv,
                            int* __restrict__ cursor, int* __restrict__ csr_src,
                            float* __restrict__ csr_norm, float* __restrict__ csr_w) {
    int e = blockIdx.x * blockDim.x + threadIdx.x;
    if (e >= N_EDGES) return;
    int r = row[e], c = col[e];
    float w = ew[e];
    int pos = atomicAdd(&cursor[c], 1);
    csr_src[pos]  = r;
    csr_norm[pos] = dinv[r] * w * dinv[c];
    csr_w[pos]    = w;
}

// ---------------- propagation (gather form, no atomics) ----------------

// hout[i][:] = dinv[i]^2 * hin[i][:] + sum_in csr_norm * hin[src][:]
__global__ void sgc_gather_k(const int* __restrict__ rowptr, const int* __restrict__ csr_src,
                             const float* __restrict__ csr_norm, const float* __restrict__ dinv,
                             const float* __restrict__ hin, float* __restrict__ hout) {
    int idx = blockIdx.x * blockDim.x + threadIdx.x;
    if (idx >= N_NODES * FCH) return;       // 1.2M
    int i = idx / FCH;
    int j = idx - i * FCH;
    int p0 = rowptr[i], p1 = rowptr[i + 1];
    float dv = dinv[i];
    float selfw = dv * dv;
    float4 v = *reinterpret_cast<const float4*>(hin + i * IN_FEAT + j * 4);
    float4 acc;
    acc.x = selfw * v.x; acc.y = selfw * v.y; acc.z = selfw * v.z; acc.w = selfw * v.w;
    for (int p = p0; p < p1; ++p) {
        int s = csr_src[p];
        float nv = csr_norm[p];
        float4 u = *reinterpret_cast<const float4*>(hin + s * IN_FEAT + j * 4);
        acc.x = fmaf(nv, u.x, acc.x);
        acc.y = fmaf(nv, u.y, acc.y);
        acc.z = fmaf(nv, u.z, acc.z);
        acc.w = fmaf(nv, u.w, acc.w);
    }
    *reinterpret_cast<float4*>(hout + i * IN_FEAT + j * 4) = acc;
}

// lout[i][:] = sum_in csr_w * lin[src][:]   (raw weights, no self-loop)
__global__ void lpa_gather_k(const int* __restrict__ rowptr, const int* __restrict__ csr_src,
                             const float* __restrict__ csr_w,
                             const float* __restrict__ lin, float* __restrict__ lout) {
    int idx = blockIdx.x * blockDim.x + threadIdx.x;
    if (idx >= N_NODES * CCH) return;       // 500k
    int i = idx / CCH;
    int j = idx - i * CCH;
    int p0 = rowptr[i], p1 = rowptr[i + 1];
    float4 acc = make_float4(0.f, 0.f, 0.f, 0.f);
    for (int p = p0; p < p1; ++p) {
        int s = csr_src[p];
        float wv = csr_w[p];
        float4 u = *reinterpret_cast<const float4*>(lin + s * NUM_CLASSES + j * 4);
        acc.x = fmaf(wv, u.x, acc.x);
        acc.y = fmaf(wv, u.y, acc.y);
        acc.z = fmaf(wv, u.z, acc.z);
        acc.w = fmaf(wv, u.w, acc.w);
    }
    *reinterpret_cast<float4*>(lout + i * NUM_CLASSES + j * 4) = acc;
}

// ---------------- dense head + LPA init ----------------

__global__ void dense_k(const float* __restrict__ h, const float* __restrict__ Wm,
                        const float* __restrict__ bias, float* __restrict__ out) {
    int idx = blockIdx.x * blockDim.x + threadIdx.x;
    if (idx >= N_NODES * NUM_CLASSES) return;   // 2M
    int i = idx / NUM_CLASSES;
    int c = idx - i * NUM_CLASSES;
    float acc = bias[c];
    const float* hr = h + i * IN_FEAT;
#pragma unroll 8
    for (int f = 0; f < IN_FEAT; ++f)
        acc = fmaf(hr[f], Wm[f * NUM_CLASSES + c], acc);
    out[idx] = acc;
}

__global__ void lpa_init_k(const int* __restrict__ y, const int* __restrict__ mask,
                           float* __restrict__ l) {
    int idx = blockIdx.x * blockDim.x + threadIdx.x;
    if (idx >= N_NODES * NUM_CLASSES) return;   // 2M
    int i = idx / NUM_CLASSES;
    int c = idx - i * NUM_CLASSES;
    l[idx] = (mask[i] != 0 && y[i] == c) ? 1.0f : 0.0f;
}

// ---------------- launch ----------------

extern "C" void kernel_launch(void* const* d_in, const int* in_sizes, int n_in,
                              void* d_out, int out_size, void* d_ws, size_t ws_size,
                              hipStream_t stream) {
    const float* x    = (const float*)d_in[0];
    const int*   ei   = (const int*)d_in[1];
    const int*   row  = ei;
    const int*   col  = ei + N_EDGES;
    const int*   y    = (const int*)d_in[2];
    const int*   mask = (const int*)d_in[3];
    const float* ew   = (const float*)d_in[4];
    const float* Wm   = (const float*)d_in[5];
    const float* bias = (const float*)d_in[6];
    float* out     = (float*)d_out;
    float* lpa_out = out + N_NODES * NUM_CLASSES;

    // workspace layout (element offsets all %4==0 -> 16B alignment for float4)
    int*   wsi      = (int*)d_ws;
    int*   cursor   = wsi;                     // 50000
    int*   rowptr   = cursor + 50000;          // 50004 (50001 used)
    int*   csr_src  = rowptr + 50004;          // 800000
    float* dinv     = (float*)(csr_src + 800000);  // 50000
    float* csr_norm = dinv + 50000;            // 800000
    float* csr_w    = csr_norm + 800000;       // 800000
    float* h1       = csr_w + 800000;          // 4800000
    float* h2       = h1 + (size_t)N_NODES * IN_FEAT;  // 4800000
    float* l0       = h1;                      // alias: h1 dead after hop 2
    float* l1       = h1 + (size_t)N_NODES * NUM_CLASSES;

    const int B = 256;
    auto g = [](long long n, int b) { return (int)((n + b - 1) / b); };

    // ---- CSR build ----
    hipMemsetAsync(cursor, 0, (size_t)N_NODES * sizeof(int), stream);
    count_k<<<g(N_EDGES, B), B, 0, stream>>>(col, cursor);
    scan_k<<<1, 1024, 0, stream>>>(cursor, rowptr);

    // ---- gcn_norm (weighted degree incl. self-loop) ----
    init_deg_k<<<g(N_NODES, B), B, 0, stream>>>(dinv);
    scatter_deg_k<<<g(N_EDGES, B), B, 0, stream>>>(col, ew, dinv);
    finish_dinv_k<<<g(N_NODES, B), B, 0, stream>>>(dinv);

    copy_cursor_k<<<g(N_NODES, B), B, 0, stream>>>(rowptr, cursor);
    csr_build_k<<<g(N_EDGES, B), B, 0, stream>>>(row, col, ew, dinv, cursor,
                                                 csr_src, csr_norm, csr_w);

    // ---- SGC: 2 gather hops ----
    sgc_gather_k<<<g((long long)N_NODES * FCH, B), B, 0, stream>>>(
        rowptr, csr_src, csr_norm, dinv, x, h1);
    sgc_gather_k<<<g((long long)N_NODES * FCH, B), B, 0, stream>>>(
        rowptr, csr_src, csr_norm, dinv, h1, h2);

    // ---- dense head ----
    dense_k<<<g((long long)N_NODES * NUM_CLASSES, B), B, 0, stream>>>(h2, Wm, bias, out);

    // ---- LPA: init + 3 gather iterations (l0 aliases h1, now dead) ----
    lpa_init_k<<<g((long long)N_NODES * NUM_CLASSES, B), B, 0, stream>>>(y, mask, l0);
    lpa_gather_k<<<g((long long)N_NODES * CCH, B), B, 0, stream>>>(
        rowptr, csr_src, csr_w, l0, l1);
    lpa_gather_k<<<g((long long)N_NODES * CCH, B), B, 0, stream>>>(
        rowptr, csr_src, csr_w, l1, l0);
    lpa_gather_k<<<g((long long)N_NODES * CCH, B), B, 0, stream>>>(
        rowptr, csr_src, csr_w, l0, lpa_out);
}

// Round 7
// 366.784 us; speedup vs baseline: 10.1621x; 1.5111x over previous
//
#include <hip/hip_runtime.h>

constexpr int N_NODES     = 50000;
constexpr int N_EDGES     = 800000;
constexpr int IN_FEAT     = 96;
constexpr int NUM_CLASSES = 40;
constexpr int CCH = NUM_CLASSES / 4;          // 10 float4 chunks per 40-wide row
constexpr int SCAN_B = 1024;
constexpr int NSCAN = (N_NODES + SCAN_B - 1) / SCAN_B;  // 49 blocks

__device__ __forceinline__ void atomAddF(float* p, float v) {
    unsafeAtomicAdd(p, v);  // native global_atomic_add_f32
}

// ---- 1 edge pass: in-degree count (int) + weighted degree (float) ----
__global__ void count_deg_k(const int* __restrict__ col, const float* __restrict__ ew,
                            int* __restrict__ cnt, float* __restrict__ deg) {
    int e = blockIdx.x * blockDim.x + threadIdx.x;
    if (e >= N_EDGES) return;
    int c = col[e];
    atomicAdd(&cnt[c], 1);
    atomAddF(&deg[c], ew[e]);
}

// ---- 3-stage parallel exclusive scan of cnt[0..N_NODES) ----
__global__ __launch_bounds__(SCAN_B) void scan1_k(const int* __restrict__ cnt,
                                                  int* __restrict__ pscan,
                                                  int* __restrict__ bsum) {
    __shared__ int buf[SCAN_B];
    int tid = threadIdx.x;
    int i = blockIdx.x * SCAN_B + tid;
    int v = (i < N_NODES) ? cnt[i] : 0;
    buf[tid] = v;
    __syncthreads();
    for (int off = 1; off < SCAN_B; off <<= 1) {
        int t = (tid >= off) ? buf[tid - off] : 0;
        __syncthreads();
        buf[tid] += t;
        __syncthreads();
    }
    if (i < N_NODES) pscan[i] = buf[tid] - v;        // block-local exclusive
    if (tid == SCAN_B - 1) bsum[blockIdx.x] = buf[tid];
}

__global__ void scan2_k(const int* __restrict__ bsum, int* __restrict__ boff,
                        int* __restrict__ rowptr) {
    __shared__ int buf[64];
    int tid = threadIdx.x;                            // 64 threads
    int v = (tid < NSCAN) ? bsum[tid] : 0;
    buf[tid] = v;
    __syncthreads();
    for (int off = 1; off < 64; off <<= 1) {
        int t = (tid >= off) ? buf[tid - off] : 0;
        __syncthreads();
        buf[tid] += t;
        __syncthreads();
    }
    boff[tid] = buf[tid] - v;                         // exclusive block offsets
    if (tid == NSCAN - 1) rowptr[N_NODES] = buf[tid]; // total == N_EDGES
}

// apply offsets; also copy cursor and finish dinv (deg -> rsqrt in place)
__global__ void scan3_k(const int* __restrict__ pscan, const int* __restrict__ boff,
                        int* __restrict__ rowptr, int* __restrict__ cursor,
                        float* __restrict__ deg) {
    int i = blockIdx.x * blockDim.x + threadIdx.x;
    if (i >= N_NODES) return;
    int rp = boff[i >> 10] + pscan[i];
    rowptr[i] = rp;
    cursor[i] = rp;
    float d = 1.0f + deg[i];                          // + self-loop weight
    deg[i] = d > 0.0f ? rsqrtf(d) : 0.0f;             // becomes dinv
}

// ---- CSR fill: src id, gcn-norm weight, raw weight ----
__global__ void csr_build_k(const int* __restrict__ row, const int* __restrict__ col,
                            const float* __restrict__ ew, const float* __restrict__ dinv,
                            int* __restrict__ cursor, int* __restrict__ csr_src,
                            float* __restrict__ csr_norm, float* __restrict__ csr_w) {
    int e = blockIdx.x * blockDim.x + threadIdx.x;
    if (e >= N_EDGES) return;
    int r = row[e], c = col[e];
    float w = ew[e];
    int pos = atomicAdd(&cursor[c], 1);
    csr_src[pos]  = r;
    csr_norm[pos] = dinv[r] * w * dinv[c];
    csr_w[pos]    = w;
}

// ---- xw = x @ W  (project BEFORE propagating: (A^2 x)W == A^2 (xW)) ----
__global__ __launch_bounds__(256) void xw_k(const float* __restrict__ x,
                                            const float* __restrict__ Wm,
                                            float* __restrict__ xw) {
    __shared__ float4 Ws[IN_FEAT * CCH];              // 96 x 10 float4 = 15 KiB
    int tid = threadIdx.x;
    for (int t = tid; t < IN_FEAT * CCH; t += 256)
        Ws[t] = reinterpret_cast<const float4*>(Wm)[t];
    __syncthreads();
    int idx = blockIdx.x * 256 + tid;
    if (idx >= N_NODES * CCH) return;                 // 500k
    int i = idx / CCH;
    int j = idx - i * CCH;
    const float* xr = x + i * IN_FEAT;
    float4 acc = make_float4(0.f, 0.f, 0.f, 0.f);
#pragma unroll
    for (int f = 0; f < IN_FEAT; ++f) {
        float xv = xr[f];
        float4 w = Ws[f * CCH + j];
        acc.x = fmaf(xv, w.x, acc.x);
        acc.y = fmaf(xv, w.y, acc.y);
        acc.z = fmaf(xv, w.z, acc.z);
        acc.w = fmaf(xv, w.w, acc.w);
    }
    reinterpret_cast<float4*>(xw + i * NUM_CLASSES)[j] = acc;
}

// ---- SGC hop at width 40: hout[i] = dinv[i]^2*hin[i] + sum norm*hin[src] (+bias) ----
__global__ void sgc_gather40_k(const int* __restrict__ rowptr, const int* __restrict__ csr_src,
                               const float* __restrict__ csr_norm, const float* __restrict__ dinv,
                               const float* __restrict__ hin, float* __restrict__ hout,
                               const float* __restrict__ bias) {
    int idx = blockIdx.x * blockDim.x + threadIdx.x;
    if (idx >= N_NODES * CCH) return;                 // 500k
    int i = idx / CCH;
    int j = idx - i * CCH;
    int p0 = rowptr[i], p1 = rowptr[i + 1];
    float dv = dinv[i];
    float selfw = dv * dv;
    float4 v = reinterpret_cast<const float4*>(hin + i * NUM_CLASSES)[j];
    float4 acc;
    acc.x = selfw * v.x; acc.y = selfw * v.y; acc.z = selfw * v.z; acc.w = selfw * v.w;
    for (int p = p0; p < p1; ++p) {
        int s = csr_src[p];
        float nv = csr_norm[p];
        float4 u = reinterpret_cast<const float4*>(hin + s * NUM_CLASSES)[j];
        acc.x = fmaf(nv, u.x, acc.x);
        acc.y = fmaf(nv, u.y, acc.y);
        acc.z = fmaf(nv, u.z, acc.z);
        acc.w = fmaf(nv, u.w, acc.w);
    }
    if (bias) {
        float4 b = reinterpret_cast<const float4*>(bias)[j];
        acc.x += b.x; acc.y += b.y; acc.z += b.z; acc.w += b.w;
    }
    reinterpret_cast<float4*>(hout + i * NUM_CLASSES)[j] = acc;
}

// ---- LPA iteration: lout[i] = sum w*lin[src] ----
__global__ void lpa_gather_k(const int* __restrict__ rowptr, const int* __restrict__ csr_src,
                             const float* __restrict__ csr_w,
                             const float* __restrict__ lin, float* __restrict__ lout) {
    int idx = blockIdx.x * blockDim.x + threadIdx.x;
    if (idx >= N_NODES * CCH) return;                 // 500k
    int i = idx / CCH;
    int j = idx - i * CCH;
    int p0 = rowptr[i], p1 = rowptr[i + 1];
    float4 acc = make_float4(0.f, 0.f, 0.f, 0.f);
    for (int p = p0; p < p1; ++p) {
        int s = csr_src[p];
        float wv = csr_w[p];
        float4 u = reinterpret_cast<const float4*>(lin + s * NUM_CLASSES)[j];
        acc.x = fmaf(wv, u.x, acc.x);
        acc.y = fmaf(wv, u.y, acc.y);
        acc.z = fmaf(wv, u.z, acc.z);
        acc.w = fmaf(wv, u.w, acc.w);
    }
    reinterpret_cast<float4*>(lout + i * NUM_CLASSES)[j] = acc;
}

__global__ void lpa_init_k(const int* __restrict__ y, const int* __restrict__ mask,
                           float* __restrict__ l) {
    int idx = blockIdx.x * blockDim.x + threadIdx.x;
    if (idx >= N_NODES * NUM_CLASSES) return;         // 2M
    int i = idx / NUM_CLASSES;
    int c = idx - i * NUM_CLASSES;
    l[idx] = (mask[i] != 0 && y[i] == c) ? 1.0f : 0.0f;
}

// ---------------- launch ----------------

extern "C" void kernel_launch(void* const* d_in, const int* in_sizes, int n_in,
                              void* d_out, int out_size, void* d_ws, size_t ws_size,
                              hipStream_t stream) {
    const float* x    = (const float*)d_in[0];
    const int*   ei   = (const int*)d_in[1];
    const int*   row  = ei;
    const int*   col  = ei + N_EDGES;
    const int*   y    = (const int*)d_in[2];
    const int*   mask = (const int*)d_in[3];
    const float* ew   = (const float*)d_in[4];
    const float* Wm   = (const float*)d_in[5];
    const float* bias = (const float*)d_in[6];
    float* out     = (float*)d_out;
    float* lpa_out = out + N_NODES * NUM_CLASSES;

    // workspace layout (element offsets %4==0 -> 16B alignment for float4)
    int*   cnt      = (int*)d_ws;                         // 50000
    float* deg      = (float*)(cnt + 50000);              // 50000 (becomes dinv)
    int*   pscan    = (int*)(deg + 50000);                // 50048
    int*   bsum     = pscan + 50048;                      // 64
    int*   boff     = bsum + 64;                          // 64
    int*   rowptr   = boff + 64;                          // 50004
    int*   cursor   = rowptr + 50004;                     // 50000
    int*   csr_src  = cursor + 50000;                     // 800000
    float* csr_norm = (float*)(csr_src + 800000);         // 800000
    float* csr_w    = csr_norm + 800000;                  // 800000
    float* xw       = csr_w + 800000;                     // 2000000
    float* g1       = xw + (size_t)N_NODES * NUM_CLASSES; // 2000000
    float* l0       = g1 + (size_t)N_NODES * NUM_CLASSES; // 2000000
    float* l1       = l0 + (size_t)N_NODES * NUM_CLASSES; // 2000000

    const int B = 256;
    auto g = [](long long n, int b) { return (int)((n + b - 1) / b); };
    float* dinv = deg;  // after scan3_k

    // ---- degree + count (one memset covers cnt and deg, both zero) ----
    hipMemsetAsync(cnt, 0, 2u * 50000u * sizeof(int), stream);
    count_deg_k<<<g(N_EDGES, B), B, 0, stream>>>(col, ew, cnt, deg);

    // ---- parallel scan -> rowptr, cursor, dinv ----
    scan1_k<<<NSCAN, SCAN_B, 0, stream>>>(cnt, pscan, bsum);
    scan2_k<<<1, 64, 0, stream>>>(bsum, boff, rowptr);
    scan3_k<<<g(N_NODES, B), B, 0, stream>>>(pscan, boff, rowptr, cursor, deg);

    // ---- CSR fill ----
    csr_build_k<<<g(N_EDGES, B), B, 0, stream>>>(row, col, ew, dinv, cursor,
                                                 csr_src, csr_norm, csr_w);

    // ---- project first: xw = x @ W ----
    xw_k<<<g((long long)N_NODES * CCH, B), B, 0, stream>>>(x, Wm, xw);

    // ---- SGC: 2 gather hops at width 40; bias fused into hop 2 ----
    sgc_gather40_k<<<g((long long)N_NODES * CCH, B), B, 0, stream>>>(
        rowptr, csr_src, csr_norm, dinv, xw, g1, nullptr);
    sgc_gather40_k<<<g((long long)N_NODES * CCH, B), B, 0, stream>>>(
        rowptr, csr_src, csr_norm, dinv, g1, out, bias);

    // ---- LPA: init + 3 gather iterations ----
    lpa_init_k<<<g((long long)N_NODES * NUM_CLASSES, B), B, 0, stream>>>(y, mask, l0);
    lpa_gather_k<<<g((long long)N_NODES * CCH, B), B, 0, stream>>>(
        rowptr, csr_src, csr_w, l0, l1);
    lpa_gather_k<<<g((long long)N_NODES * CCH, B), B, 0, stream>>>(
        rowptr, csr_src, csr_w, l1, l0);
    lpa_gather_k<<<g((long long)N_NODES * CCH, B), B, 0, stream>>>(
        rowptr, csr_src, csr_w, l0, lpa_out);
}

// Round 8
// 307.819 us; speedup vs baseline: 12.1088x; 1.1916x over previous
//
#include <hip/hip_runtime.h>

constexpr int N_NODES     = 50000;
constexpr int N_EDGES     = 800000;
constexpr int IN_FEAT     = 96;
constexpr int NUM_CLASSES = 40;
constexpr int CCH = NUM_CLASSES / 4;          // 10 float4 chunks per 40-wide row
constexpr int SCAN_B = 1024;
constexpr int NSCAN = (N_NODES + SCAN_B - 1) / SCAN_B;  // 49 blocks

// ---- pass A: per-edge in-bucket rank + bucket count (the only atomic pass) ----
__global__ void rank_k(const int* __restrict__ col, int* __restrict__ cnt,
                       int* __restrict__ rank) {
    int e = blockIdx.x * blockDim.x + threadIdx.x;
    if (e >= N_EDGES) return;
    rank[e] = atomicAdd(&cnt[col[e]], 1);
}

// ---- 3-stage parallel exclusive scan of cnt[0..N_NODES) -> rowptr ----
__global__ __launch_bounds__(SCAN_B) void scan1_k(const int* __restrict__ cnt,
                                                  int* __restrict__ pscan,
                                                  int* __restrict__ bsum) {
    __shared__ int buf[SCAN_B];
    int tid = threadIdx.x;
    int i = blockIdx.x * SCAN_B + tid;
    int v = (i < N_NODES) ? cnt[i] : 0;
    buf[tid] = v;
    __syncthreads();
    for (int off = 1; off < SCAN_B; off <<= 1) {
        int t = (tid >= off) ? buf[tid - off] : 0;
        __syncthreads();
        buf[tid] += t;
        __syncthreads();
    }
    if (i < N_NODES) pscan[i] = buf[tid] - v;        // block-local exclusive
    if (tid == SCAN_B - 1) bsum[blockIdx.x] = buf[tid];
}

__global__ void scan2_k(const int* __restrict__ bsum, int* __restrict__ boff,
                        int* __restrict__ rowptr) {
    __shared__ int buf[64];
    int tid = threadIdx.x;                            // 64 threads
    int v = (tid < NSCAN) ? bsum[tid] : 0;
    buf[tid] = v;
    __syncthreads();
    for (int off = 1; off < 64; off <<= 1) {
        int t = (tid >= off) ? buf[tid - off] : 0;
        __syncthreads();
        buf[tid] += t;
        __syncthreads();
    }
    boff[tid] = buf[tid] - v;                         // exclusive block offsets
    if (tid == NSCAN - 1) rowptr[N_NODES] = buf[tid]; // total == N_EDGES
}

__global__ void scan3_k(const int* __restrict__ pscan, const int* __restrict__ boff,
                        int* __restrict__ rowptr) {
    int i = blockIdx.x * blockDim.x + threadIdx.x;
    if (i < N_NODES) rowptr[i] = boff[i >> 10] + pscan[i];
}

// ---- pass B: CSR fill, atomic-free (pos = rowptr[c] + rank[e]) ----
__global__ void fill_k(const int* __restrict__ row, const int* __restrict__ col,
                       const float* __restrict__ ew, const int* __restrict__ rowptr,
                       const int* __restrict__ rank,
                       int* __restrict__ csr_src, float* __restrict__ csr_w) {
    int e = blockIdx.x * blockDim.x + threadIdx.x;
    if (e >= N_EDGES) return;
    int c = col[e];
    int pos = rowptr[c] + rank[e];
    csr_src[pos] = row[e];
    csr_w[pos]   = ew[e];
}

// ---- per-node: weighted degree (incl. self-loop) -> dinv; masked label ym ----
__global__ void node_prep_k(const int* __restrict__ rowptr, const float* __restrict__ csr_w,
                            const int* __restrict__ y, const int* __restrict__ mask,
                            float* __restrict__ dinv, int* __restrict__ ym) {
    int i = blockIdx.x * blockDim.x + threadIdx.x;
    if (i >= N_NODES) return;
    int p0 = rowptr[i], p1 = rowptr[i + 1];
    float d = 1.0f;                                   // self-loop weight
    for (int p = p0; p < p1; ++p) d += csr_w[p];
    dinv[i] = d > 0.0f ? rsqrtf(d) : 0.0f;
    ym[i] = (mask[i] != 0) ? y[i] : -1;
}

// ---- per-node: gcn-norm weights (sequential writes, random L2-hot dinv reads) ----
__global__ void norm_fill_k(const int* __restrict__ rowptr, const int* __restrict__ csr_src,
                            const float* __restrict__ csr_w, const float* __restrict__ dinv,
                            float* __restrict__ csr_norm) {
    int i = blockIdx.x * blockDim.x + threadIdx.x;
    if (i >= N_NODES) return;
    int p0 = rowptr[i], p1 = rowptr[i + 1];
    float dc = dinv[i];
    for (int p = p0; p < p1; ++p)
        csr_norm[p] = dinv[csr_src[p]] * csr_w[p] * dc;
}

// ---- xw = x @ W  (project BEFORE propagating: (A^2 x)W == A^2 (xW)) ----
__global__ __launch_bounds__(256) void xw_k(const float* __restrict__ x,
                                            const float* __restrict__ Wm,
                                            float* __restrict__ xw) {
    __shared__ float4 Ws[IN_FEAT * CCH];              // 96 x 10 float4 = 15 KiB
    int tid = threadIdx.x;
    for (int t = tid; t < IN_FEAT * CCH; t += 256)
        Ws[t] = reinterpret_cast<const float4*>(Wm)[t];
    __syncthreads();
    int idx = blockIdx.x * 256 + tid;
    if (idx >= N_NODES * CCH) return;                 // 500k
    int i = idx / CCH;
    int j = idx - i * CCH;
    const float* xr = x + i * IN_FEAT;
    float4 acc = make_float4(0.f, 0.f, 0.f, 0.f);
#pragma unroll
    for (int f = 0; f < IN_FEAT; ++f) {
        float xv = xr[f];
        float4 w = Ws[f * CCH + j];
        acc.x = fmaf(xv, w.x, acc.x);
        acc.y = fmaf(xv, w.y, acc.y);
        acc.z = fmaf(xv, w.z, acc.z);
        acc.w = fmaf(xv, w.w, acc.w);
    }
    reinterpret_cast<float4*>(xw + i * NUM_CLASSES)[j] = acc;
}

// ---- SGC hop at width 40: hout[i] = dinv[i]^2*hin[i] + sum norm*hin[src] (+bias) ----
__global__ void sgc_gather40_k(const int* __restrict__ rowptr, const int* __restrict__ csr_src,
                               const float* __restrict__ csr_norm, const float* __restrict__ dinv,
                               const float* __restrict__ hin, float* __restrict__ hout,
                               const float* __restrict__ bias) {
    int idx = blockIdx.x * blockDim.x + threadIdx.x;
    if (idx >= N_NODES * CCH) return;                 // 500k
    int i = idx / CCH;
    int j = idx - i * CCH;
    int p0 = rowptr[i], p1 = rowptr[i + 1];
    float dv = dinv[i];
    float selfw = dv * dv;
    float4 v = reinterpret_cast<const float4*>(hin + i * NUM_CLASSES)[j];
    float4 acc;
    acc.x = selfw * v.x; acc.y = selfw * v.y; acc.z = selfw * v.z; acc.w = selfw * v.w;
    for (int p = p0; p < p1; ++p) {
        int s = csr_src[p];
        float nv = csr_norm[p];
        float4 u = reinterpret_cast<const float4*>(hin + s * NUM_CLASSES)[j];
        acc.x = fmaf(nv, u.x, acc.x);
        acc.y = fmaf(nv, u.y, acc.y);
        acc.z = fmaf(nv, u.z, acc.z);
        acc.w = fmaf(nv, u.w, acc.w);
    }
    if (bias) {
        float4 b = reinterpret_cast<const float4*>(bias)[j];
        acc.x += b.x; acc.y += b.y; acc.z += b.z; acc.w += b.w;
    }
    reinterpret_cast<float4*>(hout + i * NUM_CLASSES)[j] = acc;
}

// ---- LPA iteration 1, sparse: input is masked one-hot -> read ym[s] only ----
__global__ void lpa1_k(const int* __restrict__ rowptr, const int* __restrict__ csr_src,
                       const float* __restrict__ csr_w, const int* __restrict__ ym,
                       float* __restrict__ lout) {
    int idx = blockIdx.x * blockDim.x + threadIdx.x;
    if (idx >= N_NODES * CCH) return;                 // 500k
    int i = idx / CCH;
    int j = idx - i * CCH;
    int p0 = rowptr[i], p1 = rowptr[i + 1];
    int base = j << 2;
    float4 acc = make_float4(0.f, 0.f, 0.f, 0.f);
    for (int p = p0; p < p1; ++p) {
        int t = ym[csr_src[p]];
        float wv = csr_w[p];
        int d = t - base;
        acc.x += (d == 0) ? wv : 0.0f;
        acc.y += (d == 1) ? wv : 0.0f;
        acc.z += (d == 2) ? wv : 0.0f;
        acc.w += (d == 3) ? wv : 0.0f;
    }
    reinterpret_cast<float4*>(lout + i * NUM_CLASSES)[j] = acc;
}

// ---- LPA iteration: lout[i] = sum w*lin[src] ----
__global__ void lpa_gather_k(const int* __restrict__ rowptr, const int* __restrict__ csr_src,
                             const float* __restrict__ csr_w,
                             const float* __restrict__ lin, float* __restrict__ lout) {
    int idx = blockIdx.x * blockDim.x + threadIdx.x;
    if (idx >= N_NODES * CCH) return;                 // 500k
    int i = idx / CCH;
    int j = idx - i * CCH;
    int p0 = rowptr[i], p1 = rowptr[i + 1];
    float4 acc = make_float4(0.f, 0.f, 0.f, 0.f);
    for (int p = p0; p < p1; ++p) {
        int s = csr_src[p];
        float wv = csr_w[p];
        float4 u = reinterpret_cast<const float4*>(lin + s * NUM_CLASSES)[j];
        acc.x = fmaf(wv, u.x, acc.x);
        acc.y = fmaf(wv, u.y, acc.y);
        acc.z = fmaf(wv, u.z, acc.z);
        acc.w = fmaf(wv, u.w, acc.w);
    }
    reinterpret_cast<float4*>(lout + i * NUM_CLASSES)[j] = acc;
}

// ---------------- launch ----------------

extern "C" void kernel_launch(void* const* d_in, const int* in_sizes, int n_in,
                              void* d_out, int out_size, void* d_ws, size_t ws_size,
                              hipStream_t stream) {
    const float* x    = (const float*)d_in[0];
    const int*   ei   = (const int*)d_in[1];
    const int*   row  = ei;
    const int*   col  = ei + N_EDGES;
    const int*   y    = (const int*)d_in[2];
    const int*   mask = (const int*)d_in[3];
    const float* ew   = (const float*)d_in[4];
    const float* Wm   = (const float*)d_in[5];
    const float* bias = (const float*)d_in[6];
    float* out     = (float*)d_out;
    float* lpa_out = out + N_NODES * NUM_CLASSES;

    // workspace layout (element offsets %4==0 -> 16B alignment for float4 regions)
    int*   cnt      = (int*)d_ws;                         // 50000
    int*   pscan    = cnt + 50000;                        // 50048
    int*   bsum     = pscan + 50048;                      // 64
    int*   boff     = bsum + 64;                          // 64
    int*   rowptr   = boff + 64;                          // 50004
    int*   rank     = rowptr + 50004;                     // 800000
    int*   csr_src  = rank + 800000;                      // 800000
    int*   ym       = csr_src + 800000;                   // 50000
    float* dinv     = (float*)(ym + 50000);               // 50000
    float* csr_w    = dinv + 50000;                       // 800000
    float* csr_norm = csr_w + 800000;                     // 800000
    float* xw       = csr_norm + 800000;                  // 2000000
    float* g1       = xw + (size_t)N_NODES * NUM_CLASSES; // 2000000
    float* lA       = g1 + (size_t)N_NODES * NUM_CLASSES; // 2000000
    float* lB       = lA + (size_t)N_NODES * NUM_CLASSES; // 2000000

    const int B = 256;
    auto g = [](long long n, int b) { return (int)((n + b - 1) / b); };

    // ---- CSR build: rank pass (only atomic pass) -> scan -> atomic-free fill ----
    hipMemsetAsync(cnt, 0, 50000u * sizeof(int), stream);
    rank_k<<<g(N_EDGES, B), B, 0, stream>>>(col, cnt, rank);
    scan1_k<<<NSCAN, SCAN_B, 0, stream>>>(cnt, pscan, bsum);
    scan2_k<<<1, 64, 0, stream>>>(bsum, boff, rowptr);
    scan3_k<<<g(N_NODES, B), B, 0, stream>>>(pscan, boff, rowptr);
    fill_k<<<g(N_EDGES, B), B, 0, stream>>>(row, col, ew, rowptr, rank, csr_src, csr_w);

    // ---- per-node prep: weighted degree -> dinv; masked labels; then norm fill ----
    node_prep_k<<<g(N_NODES, B), B, 0, stream>>>(rowptr, csr_w, y, mask, dinv, ym);
    norm_fill_k<<<g(N_NODES, B), B, 0, stream>>>(rowptr, csr_src, csr_w, dinv, csr_norm);

    // ---- project first: xw = x @ W ----
    xw_k<<<g((long long)N_NODES * CCH, B), B, 0, stream>>>(x, Wm, xw);

    // ---- SGC: 2 gather hops at width 40; bias fused into hop 2 ----
    sgc_gather40_k<<<g((long long)N_NODES * CCH, B), B, 0, stream>>>(
        rowptr, csr_src, csr_norm, dinv, xw, g1, nullptr);
    sgc_gather40_k<<<g((long long)N_NODES * CCH, B), B, 0, stream>>>(
        rowptr, csr_src, csr_norm, dinv, g1, out, bias);

    // ---- LPA: sparse iter1 (init fused) + 2 dense gathers ----
    lpa1_k<<<g((long long)N_NODES * CCH, B), B, 0, stream>>>(
        rowptr, csr_src, csr_w, ym, lA);
    lpa_gather_k<<<g((long long)N_NODES * CCH, B), B, 0, stream>>>(
        rowptr, csr_src, csr_w, lA, lB);
    lpa_gather_k<<<g((long long)N_NODES * CCH, B), B, 0, stream>>>(
        rowptr, csr_src, csr_w, lB, lpa_out);
}

// Round 10
// 287.285 us; speedup vs baseline: 12.9742x; 1.0715x over previous
//
#include <hip/hip_runtime.h>

constexpr int N_NODES     = 50000;
constexpr int N_EDGES     = 800000;
constexpr int IN_FEAT     = 96;
constexpr int NUM_CLASSES = 40;
constexpr int CCH = NUM_CLASSES / 4;          // 10 float4 chunks (xw_k)
constexpr int CH8 = NUM_CLASSES / 8;          // 5 chunks of 8 floats (gathers)
constexpr int SCAN_B = 1024;
constexpr int NSCAN = (N_NODES + SCAN_B - 1) / SCAN_B;  // 49 blocks

// ---- pass A: per-edge in-bucket rank + bucket count (the only atomic pass) ----
__global__ void rank_k(const int* __restrict__ col, int* __restrict__ cnt,
                       int* __restrict__ rank) {
    int e = blockIdx.x * blockDim.x + threadIdx.x;
    if (e >= N_EDGES) return;
    rank[e] = atomicAdd(&cnt[col[e]], 1);
}

// ---- 3-stage parallel exclusive scan of cnt[0..N_NODES) -> rowptr ----
__global__ __launch_bounds__(SCAN_B) void scan1_k(const int* __restrict__ cnt,
                                                  int* __restrict__ pscan,
                                                  int* __restrict__ bsum) {
    __shared__ int buf[SCAN_B];
    int tid = threadIdx.x;
    int i = blockIdx.x * SCAN_B + tid;
    int v = (i < N_NODES) ? cnt[i] : 0;
    buf[tid] = v;
    __syncthreads();
    for (int off = 1; off < SCAN_B; off <<= 1) {
        int t = (tid >= off) ? buf[tid - off] : 0;
        __syncthreads();
        buf[tid] += t;
        __syncthreads();
    }
    if (i < N_NODES) pscan[i] = buf[tid] - v;        // block-local exclusive
    if (tid == SCAN_B - 1) bsum[blockIdx.x] = buf[tid];
}

__global__ void scan2_k(const int* __restrict__ bsum, int* __restrict__ boff,
                        int* __restrict__ rowptr) {
    __shared__ int buf[64];
    int tid = threadIdx.x;                            // 64 threads
    int v = (tid < NSCAN) ? bsum[tid] : 0;
    buf[tid] = v;
    __syncthreads();
    for (int off = 1; off < 64; off <<= 1) {
        int t = (tid >= off) ? buf[tid - off] : 0;
        __syncthreads();
        buf[tid] += t;
        __syncthreads();
    }
    boff[tid] = buf[tid] - v;                         // exclusive block offsets
    if (tid == NSCAN - 1) rowptr[N_NODES] = buf[tid]; // total == N_EDGES
}

__global__ void scan3_k(const int* __restrict__ pscan, const int* __restrict__ boff,
                        int* __restrict__ rowptr) {
    int i = blockIdx.x * blockDim.x + threadIdx.x;
    if (i < N_NODES) rowptr[i] = boff[i >> 10] + pscan[i];
}

// ---- pass B: CSR fill, atomic-free, packed 8 B store ----
__global__ void fill_k(const int* __restrict__ row, const int* __restrict__ col,
                       const float* __restrict__ ew, const int* __restrict__ rowptr,
                       const int* __restrict__ rank, int2* __restrict__ pair) {
    int e = blockIdx.x * blockDim.x + threadIdx.x;
    if (e >= N_EDGES) return;
    int c = col[e];
    int pos = rowptr[c] + rank[e];
    pair[pos] = make_int2(row[e], __float_as_int(ew[e]));
}

// ---- per-node: weighted degree (incl. self-loop) -> dinv; masked label ym ----
__global__ void node_prep_k(const int* __restrict__ rowptr, const int2* __restrict__ pair,
                            const int* __restrict__ y, const int* __restrict__ mask,
                            float* __restrict__ dinv, int* __restrict__ ym) {
    int i = blockIdx.x * blockDim.x + threadIdx.x;
    if (i >= N_NODES) return;
    int p0 = rowptr[i], p1 = rowptr[i + 1];
    float d = 1.0f;                                   // self-loop weight
    for (int p = p0; p < p1; ++p) d += __int_as_float(pair[p].y);
    dinv[i] = d > 0.0f ? rsqrtf(d) : 0.0f;
    ym[i] = (mask[i] != 0) ? y[i] : -1;
}

// ---- xw = x @ W  (project BEFORE propagating: (A^2 x)W == A^2 (xW)) ----
__global__ __launch_bounds__(256) void xw_k(const float* __restrict__ x,
                                            const float* __restrict__ Wm,
                                            float* __restrict__ xw) {
    __shared__ float4 Ws[IN_FEAT * CCH];              // 96 x 10 float4 = 15 KiB
    int tid = threadIdx.x;
    for (int t = tid; t < IN_FEAT * CCH; t += 256)
        Ws[t] = reinterpret_cast<const float4*>(Wm)[t];
    __syncthreads();
    int idx = blockIdx.x * 256 + tid;
    if (idx >= N_NODES * CCH) return;                 // 500k
    int i = idx / CCH;
    int j = idx - i * CCH;
    const float4* xr = reinterpret_cast<const float4*>(x + i * IN_FEAT);  // 24 f4
    float4 acc = make_float4(0.f, 0.f, 0.f, 0.f);
#pragma unroll
    for (int f4 = 0; f4 < IN_FEAT / 4; ++f4) {
        float4 xv = xr[f4];
        float4 w0 = Ws[(4 * f4 + 0) * CCH + j];
        float4 w1 = Ws[(4 * f4 + 1) * CCH + j];
        float4 w2 = Ws[(4 * f4 + 2) * CCH + j];
        float4 w3 = Ws[(4 * f4 + 3) * CCH + j];
        acc.x = fmaf(xv.x, w0.x, fmaf(xv.y, w1.x, fmaf(xv.z, w2.x, fmaf(xv.w, w3.x, acc.x))));
        acc.y = fmaf(xv.x, w0.y, fmaf(xv.y, w1.y, fmaf(xv.z, w2.y, fmaf(xv.w, w3.y, acc.y))));
        acc.z = fmaf(xv.x, w0.z, fmaf(xv.y, w1.z, fmaf(xv.z, w2.z, fmaf(xv.w, w3.z, acc.z))));
        acc.w = fmaf(xv.x, w0.w, fmaf(xv.y, w1.w, fmaf(xv.z, w2.w, fmaf(xv.w, w3.w, acc.w))));
    }
    reinterpret_cast<float4*>(xw + i * NUM_CLASSES)[j] = acc;
}

// ---- K1: fused SGC hop1 (xw -> g1, gcn-norm) + LPA iter1 (ym one-hot -> lA, raw w) ----
__global__ void fused1_k(const int* __restrict__ rowptr, const int2* __restrict__ pair,
                         const float* __restrict__ dinv, const int* __restrict__ ym,
                         const float* __restrict__ xw,
                         float* __restrict__ g1, float* __restrict__ lA) {
    int idx = blockIdx.x * blockDim.x + threadIdx.x;
    if (idx >= N_NODES * CH8) return;                 // 250k
    int i = idx / CH8;
    int j = idx - i * CH8;                            // 8-float chunk
    int p0 = rowptr[i], p1 = rowptr[i + 1];
    float dc = dinv[i];
    float selfw = dc * dc;
    const float4* vr = reinterpret_cast<const float4*>(xw + i * NUM_CLASSES) + 2 * j;
    float4 v0 = vr[0], v1 = vr[1];
    float4 s0 = make_float4(selfw * v0.x, selfw * v0.y, selfw * v0.z, selfw * v0.w);
    float4 s1 = make_float4(selfw * v1.x, selfw * v1.y, selfw * v1.z, selfw * v1.w);
    float4 a0 = make_float4(0.f, 0.f, 0.f, 0.f);
    float4 a1 = make_float4(0.f, 0.f, 0.f, 0.f);
    int base = j << 3;
    for (int p = p0; p < p1; ++p) {
        int2 pr = pair[p];
        int s = pr.x;
        float w = __int_as_float(pr.y);
        float nv = dinv[s] * (w * dc);                // gcn norm on the fly
        const float4* ur = reinterpret_cast<const float4*>(xw + s * NUM_CLASSES) + 2 * j;
        float4 u0 = ur[0], u1 = ur[1];
        int t = ym[s] - base;
        s0.x = fmaf(nv, u0.x, s0.x); s0.y = fmaf(nv, u0.y, s0.y);
        s0.z = fmaf(nv, u0.z, s0.z); s0.w = fmaf(nv, u0.w, s0.w);
        s1.x = fmaf(nv, u1.x, s1.x); s1.y = fmaf(nv, u1.y, s1.y);
        s1.z = fmaf(nv, u1.z, s1.z); s1.w = fmaf(nv, u1.w, s1.w);
        a0.x += (t == 0) ? w : 0.f; a0.y += (t == 1) ? w : 0.f;
        a0.z += (t == 2) ? w : 0.f; a0.w += (t == 3) ? w : 0.f;
        a1.x += (t == 4) ? w : 0.f; a1.y += (t == 5) ? w : 0.f;
        a1.z += (t == 6) ? w : 0.f; a1.w += (t == 7) ? w : 0.f;
    }
    float4* go = reinterpret_cast<float4*>(g1 + i * NUM_CLASSES) + 2 * j;
    go[0] = s0; go[1] = s1;
    float4* lo = reinterpret_cast<float4*>(lA + i * NUM_CLASSES) + 2 * j;
    lo[0] = a0; lo[1] = a1;
}

// ---- K2: fused SGC hop2 (g1 -> out, +bias) + LPA iter2 (lA -> lB) ----
__global__ void fused2_k(const int* __restrict__ rowptr, const int2* __restrict__ pair,
                         const float* __restrict__ dinv,
                         const float* __restrict__ g1, const float* __restrict__ lA,
                         const float* __restrict__ bias,
                         float* __restrict__ out, float* __restrict__ lB) {
    int idx = blockIdx.x * blockDim.x + threadIdx.x;
    if (idx >= N_NODES * CH8) return;                 // 250k
    int i = idx / CH8;
    int j = idx - i * CH8;
    int p0 = rowptr[i], p1 = rowptr[i + 1];
    float dc = dinv[i];
    float selfw = dc * dc;
    const float4* vr = reinterpret_cast<const float4*>(g1 + i * NUM_CLASSES) + 2 * j;
    float4 v0 = vr[0], v1 = vr[1];
    float4 s0 = make_float4(selfw * v0.x, selfw * v0.y, selfw * v0.z, selfw * v0.w);
    float4 s1 = make_float4(selfw * v1.x, selfw * v1.y, selfw * v1.z, selfw * v1.w);
    float4 a0 = make_float4(0.f, 0.f, 0.f, 0.f);
    float4 a1 = make_float4(0.f, 0.f, 0.f, 0.f);
    for (int p = p0; p < p1; ++p) {
        int2 pr = pair[p];
        int s = pr.x;
        float w = __int_as_float(pr.y);
        float nv = dinv[s] * (w * dc);
        const float4* ur = reinterpret_cast<const float4*>(g1 + s * NUM_CLASSES) + 2 * j;
        const float4* lr = reinterpret_cast<const float4*>(lA + s * NUM_CLASSES) + 2 * j;
        float4 u0 = ur[0], u1 = ur[1];
        float4 m0 = lr[0], m1 = lr[1];
        s0.x = fmaf(nv, u0.x, s0.x); s0.y = fmaf(nv, u0.y, s0.y);
        s0.z = fmaf(nv, u0.z, s0.z); s0.w = fmaf(nv, u0.w, s0.w);
        s1.x = fmaf(nv, u1.x, s1.x); s1.y = fmaf(nv, u1.y, s1.y);
        s1.z = fmaf(nv, u1.z, s1.z); s1.w = fmaf(nv, u1.w, s1.w);
        a0.x = fmaf(w, m0.x, a0.x); a0.y = fmaf(w, m0.y, a0.y);
        a0.z = fmaf(w, m0.z, a0.z); a0.w = fmaf(w, m0.w, a0.w);
        a1.x = fmaf(w, m1.x, a1.x); a1.y = fmaf(w, m1.y, a1.y);
        a1.z = fmaf(w, m1.z, a1.z); a1.w = fmaf(w, m1.w, a1.w);
    }
    const float4* br = reinterpret_cast<const float4*>(bias) + 2 * j;
    float4 b0 = br[0], b1 = br[1];
    s0.x += b0.x; s0.y += b0.y; s0.z += b0.z; s0.w += b0.w;
    s1.x += b1.x; s1.y += b1.y; s1.z += b1.z; s1.w += b1.w;
    float4* oo = reinterpret_cast<float4*>(out + i * NUM_CLASSES) + 2 * j;
    oo[0] = s0; oo[1] = s1;
    float4* lo = reinterpret_cast<float4*>(lB + i * NUM_CLASSES) + 2 * j;
    lo[0] = a0; lo[1] = a1;
}

// ---- K3: LPA iter3 (lB -> lpa_out) ----
__global__ void lpa3_k(const int* __restrict__ rowptr, const int2* __restrict__ pair,
                       const float* __restrict__ lB, float* __restrict__ lout) {
    int idx = blockIdx.x * blockDim.x + threadIdx.x;
    if (idx >= N_NODES * CH8) return;                 // 250k
    int i = idx / CH8;
    int j = idx - i * CH8;
    int p0 = rowptr[i], p1 = rowptr[i + 1];
    float4 a0 = make_float4(0.f, 0.f, 0.f, 0.f);
    float4 a1 = make_float4(0.f, 0.f, 0.f, 0.f);
    for (int p = p0; p < p1; ++p) {
        int2 pr = pair[p];
        int s = pr.x;
        float w = __int_as_float(pr.y);
        const float4* lr = reinterpret_cast<const float4*>(lB + s * NUM_CLASSES) + 2 * j;
        float4 m0 = lr[0], m1 = lr[1];
        a0.x = fmaf(w, m0.x, a0.x); a0.y = fmaf(w, m0.y, a0.y);
        a0.z = fmaf(w, m0.z, a0.z); a0.w = fmaf(w, m0.w, a0.w);
        a1.x = fmaf(w, m1.x, a1.x); a1.y = fmaf(w, m1.y, a1.y);
        a1.z = fmaf(w, m1.z, a1.z); a1.w = fmaf(w, m1.w, a1.w);
    }
    float4* lo = reinterpret_cast<float4*>(lout + i * NUM_CLASSES) + 2 * j;
    lo[0] = a0; lo[1] = a1;
}

// ---------------- launch ----------------

extern "C" void kernel_launch(void* const* d_in, const int* in_sizes, int n_in,
                              void* d_out, int out_size, void* d_ws, size_t ws_size,
                              hipStream_t stream) {
    const float* x    = (const float*)d_in[0];
    const int*   ei   = (const int*)d_in[1];
    const int*   row  = ei;
    const int*   col  = ei + N_EDGES;
    const int*   y    = (const int*)d_in[2];
    const int*   mask = (const int*)d_in[3];
    const float* ew   = (const float*)d_in[4];
    const float* Wm   = (const float*)d_in[5];
    const float* bias = (const float*)d_in[6];
    float* out     = (float*)d_out;
    float* lpa_out = out + N_NODES * NUM_CLASSES;

    // workspace layout (int units; float4 regions kept 16-B aligned)
    int*   cnt      = (int*)d_ws;                         // 50000
    int*   pscan    = cnt + 50000;                        // 50048
    int*   bsum     = pscan + 50048;                      // 64
    int*   boff     = bsum + 64;                          // 64
    int*   rowptr   = boff + 64;                          // 50004
    int*   rank     = rowptr + 50004;                     // 800000
    int*   ym       = rank + 800000;                      // 50000
    float* dinv     = (float*)(ym + 50000);               // 50000
    int2*  pair     = (int2*)(dinv + 50000);              // 800000 int2 (8-B aligned)
    float* xw       = (float*)(pair + 800000);            // 2000000 (16-B aligned)
    float* g1       = xw + (size_t)N_NODES * NUM_CLASSES; // 2000000
    float* lA       = g1 + (size_t)N_NODES * NUM_CLASSES; // 2000000
    float* lB       = lA + (size_t)N_NODES * NUM_CLASSES; // 2000000

    const int B = 256;
    auto g = [](long long n, int b) { return (int)((n + b - 1) / b); };

    // ---- CSR build: rank pass (only atomic pass) -> scan -> atomic-free fill ----
    hipMemsetAsync(cnt, 0, 50000u * sizeof(int), stream);
    rank_k<<<g(N_EDGES, B), B, 0, stream>>>(col, cnt, rank);
    scan1_k<<<NSCAN, SCAN_B, 0, stream>>>(cnt, pscan, bsum);
    scan2_k<<<1, 64, 0, stream>>>(bsum, boff, rowptr);
    scan3_k<<<g(N_NODES, B), B, 0, stream>>>(pscan, boff, rowptr);
    fill_k<<<g(N_EDGES, B), B, 0, stream>>>(row, col, ew, rowptr, rank, pair);

    // ---- per-node prep: weighted degree -> dinv; masked labels ----
    node_prep_k<<<g(N_NODES, B), B, 0, stream>>>(rowptr, pair, y, mask, dinv, ym);

    // ---- project first: xw = x @ W ----
    xw_k<<<g((long long)N_NODES * CCH, B), B, 0, stream>>>(x, Wm, xw);

    // ---- fused propagation: 3 CSR walks instead of 5 ----
    fused1_k<<<g((long long)N_NODES * CH8, B), B, 0, stream>>>(
        rowptr, pair, dinv, ym, xw, g1, lA);
    fused2_k<<<g((long long)N_NODES * CH8, B), B, 0, stream>>>(
        rowptr, pair, dinv, g1, lA, bias, out, lB);
    lpa3_k<<<g((long long)N_NODES * CH8, B), B, 0, stream>>>(
        rowptr, pair, lB, lpa_out);
}

// Round 12
// 245.229 us; speedup vs baseline: 15.1993x; 1.1715x over previous
//
#include <hip/hip_runtime.h>
#include <hip/hip_fp16.h>

constexpr int N_NODES     = 50000;
constexpr int N_EDGES     = 800000;
constexpr int IN_FEAT     = 96;
constexpr int NUM_CLASSES = 40;
constexpr int CCH = NUM_CLASSES / 4;          // 10 float4 chunks (xw_k)
constexpr int CH8 = NUM_CLASSES / 8;          // 5 chunks of 8 values (gathers)
constexpr int HS  = 64;                       // fp16 row stride (64 halves = 128 B line)
constexpr int SCAN_B = 1024;
constexpr int NSCAN = (N_NODES + SCAN_B - 1) / SCAN_B;  // 49 blocks

// ---- fp16 pack/unpack (8 values <-> uint4) ----
__device__ __forceinline__ void h8_to_f(const uint4& u, float4& lo, float4& hi) {
    float2 f0 = __half22float2(*reinterpret_cast<const __half2*>(&u.x));
    float2 f1 = __half22float2(*reinterpret_cast<const __half2*>(&u.y));
    float2 f2 = __half22float2(*reinterpret_cast<const __half2*>(&u.z));
    float2 f3 = __half22float2(*reinterpret_cast<const __half2*>(&u.w));
    lo = make_float4(f0.x, f0.y, f1.x, f1.y);
    hi = make_float4(f2.x, f2.y, f3.x, f3.y);
}
__device__ __forceinline__ uint4 f_to_h8(const float4& lo, const float4& hi) {
    uint4 u;
    *reinterpret_cast<__half2*>(&u.x) = __floats2half2_rn(lo.x, lo.y);
    *reinterpret_cast<__half2*>(&u.y) = __floats2half2_rn(lo.z, lo.w);
    *reinterpret_cast<__half2*>(&u.z) = __floats2half2_rn(hi.x, hi.y);
    *reinterpret_cast<__half2*>(&u.w) = __floats2half2_rn(hi.z, hi.w);
    return u;
}

// ---- pass A: per-edge in-bucket rank + bucket count; 4 edges/thread for ILP ----
__global__ void rank_k(const int* __restrict__ col, int* __restrict__ cnt,
                       int* __restrict__ rank) {
    int t = blockIdx.x * blockDim.x + threadIdx.x;
    if (t >= N_EDGES / 4) return;
    int4 c = reinterpret_cast<const int4*>(col)[t];
    int4 r;
    r.x = atomicAdd(&cnt[c.x], 1);
    r.y = atomicAdd(&cnt[c.y], 1);
    r.z = atomicAdd(&cnt[c.z], 1);
    r.w = atomicAdd(&cnt[c.w], 1);
    reinterpret_cast<int4*>(rank)[t] = r;
}

// ---- 3-stage parallel exclusive scan of cnt[0..N_NODES) -> rowptr ----
__global__ __launch_bounds__(SCAN_B) void scan1_k(const int* __restrict__ cnt,
                                                  int* __restrict__ pscan,
                                                  int* __restrict__ bsum) {
    __shared__ int buf[SCAN_B];
    int tid = threadIdx.x;
    int i = blockIdx.x * SCAN_B + tid;
    int v = (i < N_NODES) ? cnt[i] : 0;
    buf[tid] = v;
    __syncthreads();
    for (int off = 1; off < SCAN_B; off <<= 1) {
        int t = (tid >= off) ? buf[tid - off] : 0;
        __syncthreads();
        buf[tid] += t;
        __syncthreads();
    }
    if (i < N_NODES) pscan[i] = buf[tid] - v;        // block-local exclusive
    if (tid == SCAN_B - 1) bsum[blockIdx.x] = buf[tid];
}

__global__ void scan2_k(const int* __restrict__ bsum, int* __restrict__ boff,
                        int* __restrict__ rowptr) {
    __shared__ int buf[64];
    int tid = threadIdx.x;                            // 64 threads
    int v = (tid < NSCAN) ? bsum[tid] : 0;
    buf[tid] = v;
    __syncthreads();
    for (int off = 1; off < 64; off <<= 1) {
        int t = (tid >= off) ? buf[tid - off] : 0;
        __syncthreads();
        buf[tid] += t;
        __syncthreads();
    }
    boff[tid] = buf[tid] - v;                         // exclusive block offsets
    if (tid == NSCAN - 1) rowptr[N_NODES] = buf[tid]; // total == N_EDGES
}

__global__ void scan3_k(const int* __restrict__ pscan, const int* __restrict__ boff,
                        int* __restrict__ rowptr) {
    int i = blockIdx.x * blockDim.x + threadIdx.x;
    if (i < N_NODES) rowptr[i] = boff[i >> 10] + pscan[i];
}

// ---- pass B: CSR fill, atomic-free; 4 edges/thread ----
__global__ void fill_k(const int* __restrict__ row, const int* __restrict__ col,
                       const float* __restrict__ ew, const int* __restrict__ rowptr,
                       const int* __restrict__ rank, int2* __restrict__ pair) {
    int t = blockIdx.x * blockDim.x + threadIdx.x;
    if (t >= N_EDGES / 4) return;
    int4   c = reinterpret_cast<const int4*>(col)[t];
    int4   r = reinterpret_cast<const int4*>(row)[t];
    int4   k = reinterpret_cast<const int4*>(rank)[t];
    float4 w = reinterpret_cast<const float4*>(ew)[t];
    pair[rowptr[c.x] + k.x] = make_int2(r.x, __float_as_int(w.x));
    pair[rowptr[c.y] + k.y] = make_int2(r.y, __float_as_int(w.y));
    pair[rowptr[c.z] + k.z] = make_int2(r.z, __float_as_int(w.z));
    pair[rowptr[c.w] + k.w] = make_int2(r.w, __float_as_int(w.w));
}

// ---- per-node: weighted degree (incl. self-loop) -> dinv; masked label ym ----
__global__ void node_prep_k(const int* __restrict__ rowptr, const int2* __restrict__ pair,
                            const int* __restrict__ y, const int* __restrict__ mask,
                            float* __restrict__ dinv, int* __restrict__ ym) {
    int i = blockIdx.x * blockDim.x + threadIdx.x;
    if (i >= N_NODES) return;
    int p0 = rowptr[i], p1 = rowptr[i + 1];
    float d = 1.0f;                                   // self-loop weight
    for (int p = p0; p < p1; ++p) d += __int_as_float(pair[p].y);
    dinv[i] = d > 0.0f ? rsqrtf(d) : 0.0f;
    ym[i] = (mask[i] != 0) ? y[i] : -1;
}

// ---- xw = x @ W, output fp16 rows at stride HS ----
__global__ __launch_bounds__(256) void xw_k(const float* __restrict__ x,
                                            const float* __restrict__ Wm,
                                            __half* __restrict__ xwh) {
    __shared__ float4 Ws[IN_FEAT * CCH];              // 96 x 10 float4 = 15 KiB
    int tid = threadIdx.x;
    for (int t = tid; t < IN_FEAT * CCH; t += 256)
        Ws[t] = reinterpret_cast<const float4*>(Wm)[t];
    __syncthreads();
    int idx = blockIdx.x * 256 + tid;
    if (idx >= N_NODES * CCH) return;                 // 500k
    int i = idx / CCH;
    int j = idx - i * CCH;                            // 4-col chunk
    const float4* xr = reinterpret_cast<const float4*>(x + i * IN_FEAT);  // 24 f4
    float4 acc = make_float4(0.f, 0.f, 0.f, 0.f);
#pragma unroll
    for (int f4 = 0; f4 < IN_FEAT / 4; ++f4) {
        float4 xv = xr[f4];
        float4 w0 = Ws[(4 * f4 + 0) * CCH + j];
        float4 w1 = Ws[(4 * f4 + 1) * CCH + j];
        float4 w2 = Ws[(4 * f4 + 2) * CCH + j];
        float4 w3 = Ws[(4 * f4 + 3) * CCH + j];
        acc.x = fmaf(xv.x, w0.x, fmaf(xv.y, w1.x, fmaf(xv.z, w2.x, fmaf(xv.w, w3.x, acc.x))));
        acc.y = fmaf(xv.x, w0.y, fmaf(xv.y, w1.y, fmaf(xv.z, w2.y, fmaf(xv.w, w3.y, acc.y))));
        acc.z = fmaf(xv.x, w0.z, fmaf(xv.y, w1.z, fmaf(xv.z, w2.z, fmaf(xv.w, w3.z, acc.z))));
        acc.w = fmaf(xv.x, w0.w, fmaf(xv.y, w1.w, fmaf(xv.z, w2.w, fmaf(xv.w, w3.w, acc.w))));
    }
    uint2 h;
    *reinterpret_cast<__half2*>(&h.x) = __floats2half2_rn(acc.x, acc.y);
    *reinterpret_cast<__half2*>(&h.y) = __floats2half2_rn(acc.z, acc.w);
    reinterpret_cast<uint2*>(xwh + (size_t)i * HS)[j] = h;
}

// ---- K1: fused SGC hop1 (xwh -> g1h) + LPA iter1 (ym one-hot -> lAh) ----
__global__ void fused1_k(const int* __restrict__ rowptr, const int2* __restrict__ pair,
                         const float* __restrict__ dinv, const int* __restrict__ ym,
                         const __half* __restrict__ xwh,
                         __half* __restrict__ g1h, __half* __restrict__ lAh) {
    int idx = blockIdx.x * blockDim.x + threadIdx.x;
    if (idx >= N_NODES * CH8) return;                 // 250k
    int i = idx / CH8;
    int j = idx - i * CH8;                            // 8-col chunk
    int p0 = rowptr[i], p1 = rowptr[i + 1];
    float dc = dinv[i];
    float selfw = dc * dc;
    uint4 vh = *reinterpret_cast<const uint4*>(xwh + (size_t)i * HS + j * 8);
    float4 v0, v1; h8_to_f(vh, v0, v1);
    float4 s0 = make_float4(selfw * v0.x, selfw * v0.y, selfw * v0.z, selfw * v0.w);
    float4 s1 = make_float4(selfw * v1.x, selfw * v1.y, selfw * v1.z, selfw * v1.w);
    float4 a0 = make_float4(0.f, 0.f, 0.f, 0.f);
    float4 a1 = make_float4(0.f, 0.f, 0.f, 0.f);
    int base = j << 3;
    for (int p = p0; p < p1; ++p) {
        int2 pr = pair[p];
        int s = pr.x;
        float w = __int_as_float(pr.y);
        float nv = dinv[s] * (w * dc);                // gcn norm on the fly
        uint4 uh = *reinterpret_cast<const uint4*>(xwh + (size_t)s * HS + j * 8);
        float4 u0, u1; h8_to_f(uh, u0, u1);
        int t = ym[s] - base;
        s0.x = fmaf(nv, u0.x, s0.x); s0.y = fmaf(nv, u0.y, s0.y);
        s0.z = fmaf(nv, u0.z, s0.z); s0.w = fmaf(nv, u0.w, s0.w);
        s1.x = fmaf(nv, u1.x, s1.x); s1.y = fmaf(nv, u1.y, s1.y);
        s1.z = fmaf(nv, u1.z, s1.z); s1.w = fmaf(nv, u1.w, s1.w);
        a0.x += (t == 0) ? w : 0.f; a0.y += (t == 1) ? w : 0.f;
        a0.z += (t == 2) ? w : 0.f; a0.w += (t == 3) ? w : 0.f;
        a1.x += (t == 4) ? w : 0.f; a1.y += (t == 5) ? w : 0.f;
        a1.z += (t == 6) ? w : 0.f; a1.w += (t == 7) ? w : 0.f;
    }
    *reinterpret_cast<uint4*>(g1h + (size_t)i * HS + j * 8) = f_to_h8(s0, s1);
    *reinterpret_cast<uint4*>(lAh + (size_t)i * HS + j * 8) = f_to_h8(a0, a1);
}

// ---- K2: fused SGC hop2 (g1h -> out f32, +bias) + LPA iter2 (lAh -> lBh) ----
__global__ void fused2_k(const int* __restrict__ rowptr, const int2* __restrict__ pair,
                         const float* __restrict__ dinv,
                         const __half* __restrict__ g1h, const __half* __restrict__ lAh,
                         const float* __restrict__ bias,
                         float* __restrict__ out, __half* __restrict__ lBh) {
    int idx = blockIdx.x * blockDim.x + threadIdx.x;
    if (idx >= N_NODES * CH8) return;                 // 250k
    int i = idx / CH8;
    int j = idx - i * CH8;
    int p0 = rowptr[i], p1 = rowptr[i + 1];
    float dc = dinv[i];
    float selfw = dc * dc;
    uint4 vh = *reinterpret_cast<const uint4*>(g1h + (size_t)i * HS + j * 8);
    float4 v0, v1; h8_to_f(vh, v0, v1);
    float4 s0 = make_float4(selfw * v0.x, selfw * v0.y, selfw * v0.z, selfw * v0.w);
    float4 s1 = make_float4(selfw * v1.x, selfw * v1.y, selfw * v1.z, selfw * v1.w);
    float4 a0 = make_float4(0.f, 0.f, 0.f, 0.f);
    float4 a1 = make_float4(0.f, 0.f, 0.f, 0.f);
    for (int p = p0; p < p1; ++p) {
        int2 pr = pair[p];
        int s = pr.x;
        float w = __int_as_float(pr.y);
        float nv = dinv[s] * (w * dc);
        uint4 uh = *reinterpret_cast<const uint4*>(g1h + (size_t)s * HS + j * 8);
        uint4 mh = *reinterpret_cast<const uint4*>(lAh + (size_t)s * HS + j * 8);
        float4 u0, u1; h8_to_f(uh, u0, u1);
        float4 m0, m1; h8_to_f(mh, m0, m1);
        s0.x = fmaf(nv, u0.x, s0.x); s0.y = fmaf(nv, u0.y, s0.y);
        s0.z = fmaf(nv, u0.z, s0.z); s0.w = fmaf(nv, u0.w, s0.w);
        s1.x = fmaf(nv, u1.x, s1.x); s1.y = fmaf(nv, u1.y, s1.y);
        s1.z = fmaf(nv, u1.z, s1.z); s1.w = fmaf(nv, u1.w, s1.w);
        a0.x = fmaf(w, m0.x, a0.x); a0.y = fmaf(w, m0.y, a0.y);
        a0.z = fmaf(w, m0.z, a0.z); a0.w = fmaf(w, m0.w, a0.w);
        a1.x = fmaf(w, m1.x, a1.x); a1.y = fmaf(w, m1.y, a1.y);
        a1.w = fmaf(w, m1.w, a1.w); a1.z = fmaf(w, m1.z, a1.z);
    }
    const float4* br = reinterpret_cast<const float4*>(bias) + 2 * j;
    float4 b0 = br[0], b1 = br[1];
    s0.x += b0.x; s0.y += b0.y; s0.z += b0.z; s0.w += b0.w;
    s1.x += b1.x; s1.y += b1.y; s1.z += b1.z; s1.w += b1.w;
    float4* oo = reinterpret_cast<float4*>(out + (size_t)i * NUM_CLASSES) + 2 * j;
    oo[0] = s0; oo[1] = s1;                           // final SGC output: f32
    *reinterpret_cast<uint4*>(lBh + (size_t)i * HS + j * 8) = f_to_h8(a0, a1);
}

// ---- K3: LPA iter3 (lBh -> lpa_out f32) ----
__global__ void lpa3_k(const int* __restrict__ rowptr, const int2* __restrict__ pair,
                       const __half* __restrict__ lBh, float* __restrict__ lout) {
    int idx = blockIdx.x * blockDim.x + threadIdx.x;
    if (idx >= N_NODES * CH8) return;                 // 250k
    int i = idx / CH8;
    int j = idx - i * CH8;
    int p0 = rowptr[i], p1 = rowptr[i + 1];
    float4 a0 = make_float4(0.f, 0.f, 0.f, 0.f);
    float4 a1 = make_float4(0.f, 0.f, 0.f, 0.f);
    for (int p = p0; p < p1; ++p) {
        int2 pr = pair[p];
        int s = pr.x;
        float w = __int_as_float(pr.y);
        uint4 mh = *reinterpret_cast<const uint4*>(lBh + (size_t)s * HS + j * 8);
        float4 m0, m1; h8_to_f(mh, m0, m1);
        a0.x = fmaf(w, m0.x, a0.x); a0.y = fmaf(w, m0.y, a0.y);
        a0.z = fmaf(w, m0.z, a0.z); a0.w = fmaf(w, m0.w, a0.w);
        a1.x = fmaf(w, m1.x, a1.x); a1.y = fmaf(w, m1.y, a1.y);
        a1.z = fmaf(w, m1.z, a1.z); a1.w = fmaf(w, m1.w, a1.w);
    }
    float4* lo = reinterpret_cast<float4*>(lout + (size_t)i * NUM_CLASSES) + 2 * j;
    lo[0] = a0; lo[1] = a1;                           // final LPA output: f32
}

// ---------------- launch ----------------

extern "C" void kernel_launch(void* const* d_in, const int* in_sizes, int n_in,
                              void* d_out, int out_size, void* d_ws, size_t ws_size,
                              hipStream_t stream) {
    const float* x    = (const float*)d_in[0];
    const int*   ei   = (const int*)d_in[1];
    const int*   row  = ei;
    const int*   col  = ei + N_EDGES;
    const int*   y    = (const int*)d_in[2];
    const int*   mask = (const int*)d_in[3];
    const float* ew   = (const float*)d_in[4];
    const float* Wm   = (const float*)d_in[5];
    const float* bias = (const float*)d_in[6];
    float* out     = (float*)d_out;
    float* lpa_out = out + N_NODES * NUM_CLASSES;

    // workspace layout (int units; all region starts %4==0 -> 16-B aligned)
    int*    cnt    = (int*)d_ws;                          // 50000
    int*    pscan  = cnt + 50000;                         // 50048
    int*    bsum   = pscan + 50048;                       // 64
    int*    boff   = bsum + 64;                           // 64
    int*    rowptr = boff + 64;                           // 50004
    int*    rank   = rowptr + 50004;                      // 800000
    int*    ym     = rank + 800000;                       // 50000
    float*  dinv   = (float*)(ym + 50000);                // 50000
    int2*   pair   = (int2*)(dinv + 50000);               // 800000 int2
    __half* xwh    = (__half*)(pair + 800000);            // 50000*64 halves (6.4 MB)
    __half* g1h    = xwh + (size_t)N_NODES * HS;
    __half* lAh    = g1h + (size_t)N_NODES * HS;
    __half* lBh    = lAh + (size_t)N_NODES * HS;

    const int B = 256;
    auto g = [](long long n, int b) { return (int)((n + b - 1) / b); };

    // ---- CSR build: rank pass (only atomic pass) -> scan -> atomic-free fill ----
    hipMemsetAsync(cnt, 0, 50000u * sizeof(int), stream);
    rank_k<<<g(N_EDGES / 4, B), B, 0, stream>>>(col, cnt, rank);
    scan1_k<<<NSCAN, SCAN_B, 0, stream>>>(cnt, pscan, bsum);
    scan2_k<<<1, 64, 0, stream>>>(bsum, boff, rowptr);
    scan3_k<<<g(N_NODES, B), B, 0, stream>>>(pscan, boff, rowptr);
    fill_k<<<g(N_EDGES / 4, B), B, 0, stream>>>(row, col, ew, rowptr, rank, pair);

    // ---- per-node prep: weighted degree -> dinv; masked labels ----
    node_prep_k<<<g(N_NODES, B), B, 0, stream>>>(rowptr, pair, y, mask, dinv, ym);

    // ---- project first: xwh = fp16(x @ W) ----
    xw_k<<<g((long long)N_NODES * CCH, B), B, 0, stream>>>(x, Wm, xwh);

    // ---- fused propagation: 3 CSR walks, fp16 gather rows (1 cache line each) ----
    fused1_k<<<g((long long)N_NODES * CH8, B), B, 0, stream>>>(
        rowptr, pair, dinv, ym, xwh, g1h, lAh);
    fused2_k<<<g((long long)N_NODES * CH8, B), B, 0, stream>>>(
        rowptr, pair, dinv, g1h, lAh, bias, out, lBh);
    lpa3_k<<<g((long long)N_NODES * CH8, B), B, 0, stream>>>(
        rowptr, pair, lBh, lpa_out);
}

// Round 13
// 241.304 us; speedup vs baseline: 15.4465x; 1.0163x over previous
//
#include <hip/hip_runtime.h>
#include <hip/hip_fp16.h>

constexpr int N_NODES     = 50000;
constexpr int N_EDGES     = 800000;
constexpr int IN_FEAT     = 96;
constexpr int NUM_CLASSES = 40;
constexpr int CCH = NUM_CLASSES / 4;          // 10 uint2 chunks (xw_k)
constexpr int CH8 = NUM_CLASSES / 8;          // 5 chunks of 8 values (gathers)
constexpr int HS  = 64;                       // xwt row stride in halves (128 B line)
constexpr int CS  = 128;                      // comb row stride in halves (256 B)
constexpr int LS  = 64;                       // lB row stride in halves (128 B)
constexpr int SCAN_B = 1024;
constexpr int NSCAN = (N_NODES + SCAN_B - 1) / SCAN_B;  // 49 blocks

// ---- fp16 pack/unpack (8 values <-> uint4) ----
__device__ __forceinline__ void h8_to_f(const uint4& u, float4& lo, float4& hi) {
    float2 f0 = __half22float2(*reinterpret_cast<const __half2*>(&u.x));
    float2 f1 = __half22float2(*reinterpret_cast<const __half2*>(&u.y));
    float2 f2 = __half22float2(*reinterpret_cast<const __half2*>(&u.z));
    float2 f3 = __half22float2(*reinterpret_cast<const __half2*>(&u.w));
    lo = make_float4(f0.x, f0.y, f1.x, f1.y);
    hi = make_float4(f2.x, f2.y, f3.x, f3.y);
}
__device__ __forceinline__ uint4 f_to_h8(const float4& lo, const float4& hi) {
    uint4 u;
    *reinterpret_cast<__half2*>(&u.x) = __floats2half2_rn(lo.x, lo.y);
    *reinterpret_cast<__half2*>(&u.y) = __floats2half2_rn(lo.z, lo.w);
    *reinterpret_cast<__half2*>(&u.z) = __floats2half2_rn(hi.x, hi.y);
    *reinterpret_cast<__half2*>(&u.w) = __floats2half2_rn(hi.z, hi.w);
    return u;
}

// ---- pass A: per-edge in-bucket rank + bucket count; 8 edges/thread for ILP ----
__global__ void rank_k(const int* __restrict__ col, int* __restrict__ cnt,
                       int* __restrict__ rank) {
    int t = blockIdx.x * blockDim.x + threadIdx.x;
    if (t >= N_EDGES / 8) return;
    int4 c0 = reinterpret_cast<const int4*>(col)[2 * t];
    int4 c1 = reinterpret_cast<const int4*>(col)[2 * t + 1];
    int4 r0, r1;
    r0.x = atomicAdd(&cnt[c0.x], 1);
    r0.y = atomicAdd(&cnt[c0.y], 1);
    r0.z = atomicAdd(&cnt[c0.z], 1);
    r0.w = atomicAdd(&cnt[c0.w], 1);
    r1.x = atomicAdd(&cnt[c1.x], 1);
    r1.y = atomicAdd(&cnt[c1.y], 1);
    r1.z = atomicAdd(&cnt[c1.z], 1);
    r1.w = atomicAdd(&cnt[c1.w], 1);
    reinterpret_cast<int4*>(rank)[2 * t]     = r0;
    reinterpret_cast<int4*>(rank)[2 * t + 1] = r1;
}

// ---- 3-stage parallel exclusive scan of cnt[0..N_NODES) -> rowptr ----
__global__ __launch_bounds__(SCAN_B) void scan1_k(const int* __restrict__ cnt,
                                                  int* __restrict__ pscan,
                                                  int* __restrict__ bsum) {
    __shared__ int buf[SCAN_B];
    int tid = threadIdx.x;
    int i = blockIdx.x * SCAN_B + tid;
    int v = (i < N_NODES) ? cnt[i] : 0;
    buf[tid] = v;
    __syncthreads();
    for (int off = 1; off < SCAN_B; off <<= 1) {
        int t = (tid >= off) ? buf[tid - off] : 0;
        __syncthreads();
        buf[tid] += t;
        __syncthreads();
    }
    if (i < N_NODES) pscan[i] = buf[tid] - v;        // block-local exclusive
    if (tid == SCAN_B - 1) bsum[blockIdx.x] = buf[tid];
}

__global__ void scan2_k(const int* __restrict__ bsum, int* __restrict__ boff,
                        int* __restrict__ rowptr) {
    __shared__ int buf[64];
    int tid = threadIdx.x;                            // 64 threads
    int v = (tid < NSCAN) ? bsum[tid] : 0;
    buf[tid] = v;
    __syncthreads();
    for (int off = 1; off < 64; off <<= 1) {
        int t = (tid >= off) ? buf[tid - off] : 0;
        __syncthreads();
        buf[tid] += t;
        __syncthreads();
    }
    boff[tid] = buf[tid] - v;                         // exclusive block offsets
    if (tid == NSCAN - 1) rowptr[N_NODES] = buf[tid]; // total == N_EDGES
}

__global__ void scan3_k(const int* __restrict__ pscan, const int* __restrict__ boff,
                        int* __restrict__ rowptr) {
    int i = blockIdx.x * blockDim.x + threadIdx.x;
    if (i < N_NODES) rowptr[i] = boff[i >> 10] + pscan[i];
}

// ---- pass B: CSR fill, atomic-free; 4 edges/thread ----
__global__ void fill_k(const int* __restrict__ row, const int* __restrict__ col,
                       const float* __restrict__ ew, const int* __restrict__ rowptr,
                       const int* __restrict__ rank, int2* __restrict__ pair) {
    int t = blockIdx.x * blockDim.x + threadIdx.x;
    if (t >= N_EDGES / 4) return;
    int4   c = reinterpret_cast<const int4*>(col)[t];
    int4   r = reinterpret_cast<const int4*>(row)[t];
    int4   k = reinterpret_cast<const int4*>(rank)[t];
    float4 w = reinterpret_cast<const float4*>(ew)[t];
    pair[rowptr[c.x] + k.x] = make_int2(r.x, __float_as_int(w.x));
    pair[rowptr[c.y] + k.y] = make_int2(r.y, __float_as_int(w.y));
    pair[rowptr[c.z] + k.z] = make_int2(r.z, __float_as_int(w.z));
    pair[rowptr[c.w] + k.w] = make_int2(r.w, __float_as_int(w.w));
}

// ---- per-node: weighted degree -> dinv; masked label; both embedded in xwt row ----
__global__ void node_prep_k(const int* __restrict__ rowptr, const int2* __restrict__ pair,
                            const int* __restrict__ y, const int* __restrict__ mask,
                            unsigned short* __restrict__ xwt) {
    int i = blockIdx.x * blockDim.x + threadIdx.x;
    if (i >= N_NODES) return;
    int p0 = rowptr[i], p1 = rowptr[i + 1];
    float d = 1.0f;                                   // self-loop weight
    for (int p = p0; p < p1; ++p) d += __int_as_float(pair[p].y);
    float dv = d > 0.0f ? rsqrtf(d) : 0.0f;
    unsigned short* rowp = xwt + (size_t)i * HS;
    *reinterpret_cast<int*>(rowp + 40)   = (mask[i] != 0) ? y[i] : -1;  // bytes 80-84
    *reinterpret_cast<float*>(rowp + 42) = dv;                          // bytes 84-88
}

// ---- xw = x @ W -> fp16 halves [0,40) of xwt rows ----
__global__ __launch_bounds__(256) void xw_k(const float* __restrict__ x,
                                            const float* __restrict__ Wm,
                                            unsigned short* __restrict__ xwt) {
    __shared__ float4 Ws[IN_FEAT * CCH];              // 96 x 10 float4 = 15 KiB
    int tid = threadIdx.x;
    for (int t = tid; t < IN_FEAT * CCH; t += 256)
        Ws[t] = reinterpret_cast<const float4*>(Wm)[t];
    __syncthreads();
    int idx = blockIdx.x * 256 + tid;
    if (idx >= N_NODES * CCH) return;                 // 500k
    int i = idx / CCH;
    int j = idx - i * CCH;                            // 4-col chunk
    const float4* xr = reinterpret_cast<const float4*>(x + i * IN_FEAT);  // 24 f4
    float4 acc = make_float4(0.f, 0.f, 0.f, 0.f);
#pragma unroll
    for (int f4 = 0; f4 < IN_FEAT / 4; ++f4) {
        float4 xv = xr[f4];
        float4 w0 = Ws[(4 * f4 + 0) * CCH + j];
        float4 w1 = Ws[(4 * f4 + 1) * CCH + j];
        float4 w2 = Ws[(4 * f4 + 2) * CCH + j];
        float4 w3 = Ws[(4 * f4 + 3) * CCH + j];
        acc.x = fmaf(xv.x, w0.x, fmaf(xv.y, w1.x, fmaf(xv.z, w2.x, fmaf(xv.w, w3.x, acc.x))));
        acc.y = fmaf(xv.x, w0.y, fmaf(xv.y, w1.y, fmaf(xv.z, w2.y, fmaf(xv.w, w3.y, acc.y))));
        acc.z = fmaf(xv.x, w0.z, fmaf(xv.y, w1.z, fmaf(xv.z, w2.z, fmaf(xv.w, w3.z, acc.z))));
        acc.w = fmaf(xv.x, w0.w, fmaf(xv.y, w1.w, fmaf(xv.z, w2.w, fmaf(xv.w, w3.w, acc.w))));
    }
    uint2 h;
    *reinterpret_cast<__half2*>(&h.x) = __floats2half2_rn(acc.x, acc.y);
    *reinterpret_cast<__half2*>(&h.y) = __floats2half2_rn(acc.z, acc.w);
    reinterpret_cast<uint2*>(xwt + (size_t)i * HS)[j] = h;
}

// ---- K1: fused SGC hop1 + LPA iter1; reads xwt rows (1 line/edge), writes comb ----
__global__ void fused1_k(const int* __restrict__ rowptr, const int2* __restrict__ pair,
                         const unsigned short* __restrict__ xwt,
                         unsigned short* __restrict__ comb) {
    int idx = blockIdx.x * blockDim.x + threadIdx.x;
    if (idx >= N_NODES * CH8) return;                 // 250k
    int i = idx / CH8;
    int j = idx - i * CH8;                            // 8-col chunk
    int p0 = rowptr[i], p1 = rowptr[i + 1];
    const unsigned short* irow = xwt + (size_t)i * HS;
    float dc = *reinterpret_cast<const float*>(irow + 42);
    float selfw = dc * dc;
    uint4 vh = *reinterpret_cast<const uint4*>(irow + j * 8);
    float4 v0, v1; h8_to_f(vh, v0, v1);
    float4 s0 = make_float4(selfw * v0.x, selfw * v0.y, selfw * v0.z, selfw * v0.w);
    float4 s1 = make_float4(selfw * v1.x, selfw * v1.y, selfw * v1.z, selfw * v1.w);
    float4 a0 = make_float4(0.f, 0.f, 0.f, 0.f);
    float4 a1 = make_float4(0.f, 0.f, 0.f, 0.f);
    int base = j << 3;
    for (int p = p0; p < p1; ++p) {
        int2 pr = pair[p];
        int s = pr.x;
        float w = __int_as_float(pr.y);
        const unsigned short* srow = xwt + (size_t)s * HS;
        uint4 uh = *reinterpret_cast<const uint4*>(srow + j * 8);
        int   t  = *reinterpret_cast<const int*>(srow + 40) - base;
        float ds = *reinterpret_cast<const float*>(srow + 42);
        float nv = ds * (w * dc);                     // gcn norm on the fly
        float4 u0, u1; h8_to_f(uh, u0, u1);
        s0.x = fmaf(nv, u0.x, s0.x); s0.y = fmaf(nv, u0.y, s0.y);
        s0.z = fmaf(nv, u0.z, s0.z); s0.w = fmaf(nv, u0.w, s0.w);
        s1.x = fmaf(nv, u1.x, s1.x); s1.y = fmaf(nv, u1.y, s1.y);
        s1.z = fmaf(nv, u1.z, s1.z); s1.w = fmaf(nv, u1.w, s1.w);
        a0.x += (t == 0) ? w : 0.f; a0.y += (t == 1) ? w : 0.f;
        a0.z += (t == 2) ? w : 0.f; a0.w += (t == 3) ? w : 0.f;
        a1.x += (t == 4) ? w : 0.f; a1.y += (t == 5) ? w : 0.f;
        a1.z += (t == 6) ? w : 0.f; a1.w += (t == 7) ? w : 0.f;
    }
    unsigned short* crow = comb + (size_t)i * CS;
    *reinterpret_cast<uint4*>(crow + j * 8)      = f_to_h8(s0, s1);  // g1 halves [0,40)
    *reinterpret_cast<uint4*>(crow + 40 + j * 8) = f_to_h8(a0, a1);  // lA halves [40,80)
    if (j == 0) *reinterpret_cast<float*>(crow + 80) = dc;           // dinv bytes 160-164
}

// ---- K2: fused SGC hop2 (+bias -> out f32) + LPA iter2; reads comb, writes lBh ----
__global__ void fused2_k(const int* __restrict__ rowptr, const int2* __restrict__ pair,
                         const unsigned short* __restrict__ comb,
                         const float* __restrict__ bias,
                         float* __restrict__ out, unsigned short* __restrict__ lBh) {
    int idx = blockIdx.x * blockDim.x + threadIdx.x;
    if (idx >= N_NODES * CH8) return;                 // 250k
    int i = idx / CH8;
    int j = idx - i * CH8;
    int p0 = rowptr[i], p1 = rowptr[i + 1];
    const unsigned short* irow = comb + (size_t)i * CS;
    float dc = *reinterpret_cast<const float*>(irow + 80);
    float selfw = dc * dc;
    uint4 vh = *reinterpret_cast<const uint4*>(irow + j * 8);
    float4 v0, v1; h8_to_f(vh, v0, v1);
    float4 s0 = make_float4(selfw * v0.x, selfw * v0.y, selfw * v0.z, selfw * v0.w);
    float4 s1 = make_float4(selfw * v1.x, selfw * v1.y, selfw * v1.z, selfw * v1.w);
    float4 a0 = make_float4(0.f, 0.f, 0.f, 0.f);
    float4 a1 = make_float4(0.f, 0.f, 0.f, 0.f);
    for (int p = p0; p < p1; ++p) {
        int2 pr = pair[p];
        int s = pr.x;
        float w = __int_as_float(pr.y);
        const unsigned short* srow = comb + (size_t)s * CS;
        uint4 uh = *reinterpret_cast<const uint4*>(srow + j * 8);
        uint4 mh = *reinterpret_cast<const uint4*>(srow + 40 + j * 8);
        float ds = *reinterpret_cast<const float*>(srow + 80);
        float nv = ds * (w * dc);
        float4 u0, u1; h8_to_f(uh, u0, u1);
        float4 m0, m1; h8_to_f(mh, m0, m1);
        s0.x = fmaf(nv, u0.x, s0.x); s0.y = fmaf(nv, u0.y, s0.y);
        s0.z = fmaf(nv, u0.z, s0.z); s0.w = fmaf(nv, u0.w, s0.w);
        s1.x = fmaf(nv, u1.x, s1.x); s1.y = fmaf(nv, u1.y, s1.y);
        s1.z = fmaf(nv, u1.z, s1.z); s1.w = fmaf(nv, u1.w, s1.w);
        a0.x = fmaf(w, m0.x, a0.x); a0.y = fmaf(w, m0.y, a0.y);
        a0.z = fmaf(w, m0.z, a0.z); a0.w = fmaf(w, m0.w, a0.w);
        a1.x = fmaf(w, m1.x, a1.x); a1.y = fmaf(w, m1.y, a1.y);
        a1.z = fmaf(w, m1.z, a1.z); a1.w = fmaf(w, m1.w, a1.w);
    }
    const float4* br = reinterpret_cast<const float4*>(bias) + 2 * j;
    float4 b0 = br[0], b1 = br[1];
    s0.x += b0.x; s0.y += b0.y; s0.z += b0.z; s0.w += b0.w;
    s1.x += b1.x; s1.y += b1.y; s1.z += b1.z; s1.w += b1.w;
    float4* oo = reinterpret_cast<float4*>(out + (size_t)i * NUM_CLASSES) + 2 * j;
    oo[0] = s0; oo[1] = s1;                           // final SGC output: f32
    *reinterpret_cast<uint4*>(lBh + (size_t)i * LS + j * 8) = f_to_h8(a0, a1);
}

// ---- K3: LPA iter3 (lBh -> lpa_out f32) ----
__global__ void lpa3_k(const int* __restrict__ rowptr, const int2* __restrict__ pair,
                       const unsigned short* __restrict__ lBh, float* __restrict__ lout) {
    int idx = blockIdx.x * blockDim.x + threadIdx.x;
    if (idx >= N_NODES * CH8) return;                 // 250k
    int i = idx / CH8;
    int j = idx - i * CH8;
    int p0 = rowptr[i], p1 = rowptr[i + 1];
    float4 a0 = make_float4(0.f, 0.f, 0.f, 0.f);
    float4 a1 = make_float4(0.f, 0.f, 0.f, 0.f);
    for (int p = p0; p < p1; ++p) {
        int2 pr = pair[p];
        int s = pr.x;
        float w = __int_as_float(pr.y);
        uint4 mh = *reinterpret_cast<const uint4*>(lBh + (size_t)s * LS + j * 8);
        float4 m0, m1; h8_to_f(mh, m0, m1);
        a0.x = fmaf(w, m0.x, a0.x); a0.y = fmaf(w, m0.y, a0.y);
        a0.z = fmaf(w, m0.z, a0.z); a0.w = fmaf(w, m0.w, a0.w);
        a1.x = fmaf(w, m1.x, a1.x); a1.y = fmaf(w, m1.y, a1.y);
        a1.z = fmaf(w, m1.z, a1.z); a1.w = fmaf(w, m1.w, a1.w);
    }
    float4* lo = reinterpret_cast<float4*>(lout + (size_t)i * NUM_CLASSES) + 2 * j;
    lo[0] = a0; lo[1] = a1;                           // final LPA output: f32
}

// ---------------- launch ----------------

extern "C" void kernel_launch(void* const* d_in, const int* in_sizes, int n_in,
                              void* d_out, int out_size, void* d_ws, size_t ws_size,
                              hipStream_t stream) {
    const float* x    = (const float*)d_in[0];
    const int*   ei   = (const int*)d_in[1];
    const int*   row  = ei;
    const int*   col  = ei + N_EDGES;
    const int*   y    = (const int*)d_in[2];
    const int*   mask = (const int*)d_in[3];
    const float* ew   = (const float*)d_in[4];
    const float* Wm   = (const float*)d_in[5];
    const float* bias = (const float*)d_in[6];
    float* out     = (float*)d_out;
    float* lpa_out = out + N_NODES * NUM_CLASSES;

    // workspace layout: big aligned tables first (all offsets multiple of 256 B)
    unsigned short* xwt  = (unsigned short*)d_ws;               // 50000*64 u16 = 6.4 MB
    unsigned short* comb = xwt + (size_t)N_NODES * HS;          // 50000*128 u16 = 12.8 MB
    unsigned short* lBh  = comb + (size_t)N_NODES * CS;         // 50000*64 u16 = 6.4 MB
    int2* pair  = (int2*)(lBh + (size_t)N_NODES * LS);          // 800000 int2 = 6.4 MB
    int* wsi    = (int*)(pair + N_EDGES);
    int* cnt    = wsi;                                          // 50000
    int* pscan  = cnt + 50000;                                  // 50048
    int* bsum   = pscan + 50048;                                // 64
    int* boff   = bsum + 64;                                    // 64
    int* rowptr = boff + 64;                                    // 50004
    int* rank   = rowptr + 50004;                               // 800000

    const int B = 256;
    auto g = [](long long n, int b) { return (int)((n + b - 1) / b); };

    // ---- CSR build: rank pass (only atomic pass) -> scan -> atomic-free fill ----
    hipMemsetAsync(cnt, 0, 50000u * sizeof(int), stream);
    rank_k<<<g(N_EDGES / 8, B), B, 0, stream>>>(col, cnt, rank);
    scan1_k<<<NSCAN, SCAN_B, 0, stream>>>(cnt, pscan, bsum);
    scan2_k<<<1, 64, 0, stream>>>(bsum, boff, rowptr);
    scan3_k<<<g(N_NODES, B), B, 0, stream>>>(pscan, boff, rowptr);
    fill_k<<<g(N_EDGES / 4, B), B, 0, stream>>>(row, col, ew, rowptr, rank, pair);

    // ---- per-node prep: dinv + masked label embedded into xwt rows ----
    node_prep_k<<<g(N_NODES, B), B, 0, stream>>>(rowptr, pair, y, mask, xwt);

    // ---- project first: xwt[:, 0:40) = fp16(x @ W) ----
    xw_k<<<g((long long)N_NODES * CCH, B), B, 0, stream>>>(x, Wm, xwt);

    // ---- fused propagation: 3 CSR walks, 1 gathered row per edge per walk ----
    fused1_k<<<g((long long)N_NODES * CH8, B), B, 0, stream>>>(rowptr, pair, xwt, comb);
    fused2_k<<<g((long long)N_NODES * CH8, B), B, 0, stream>>>(rowptr, pair, comb,
                                                              bias, out, lBh);
    lpa3_k<<<g((long long)N_NODES * CH8, B), B, 0, stream>>>(rowptr, pair, lBh, lpa_out);
}